// Round 11
// baseline (387.006 us; speedup 1.0000x reference)
//
#include <hip/hip_runtime.h>

constexpr int B_ = 8, N_ = 10000, D_ = 128, H_ = 4, K_ = 256, M_ = 5000, DFF_ = 512;
constexpr int NPAD = 10240;   // n padded to multiple of 32 for MFMA K-loop

typedef __attribute__((ext_vector_type(8))) short bf16x8;
typedef __attribute__((ext_vector_type(4))) float f32x4;

__device__ __forceinline__ float bf2f(unsigned short u) {
    unsigned x = ((unsigned)u) << 16; float f; __builtin_memcpy(&f, &x, 4); return f;
}
__device__ __forceinline__ unsigned short f2bf(float f) {
    unsigned x; __builtin_memcpy(&x, &f, 4);
    x = (x + 0x7fffu + ((x >> 16) & 1u)) >> 16;   // RNE
    return (unsigned short)x;
}
__device__ __forceinline__ unsigned pack2(float a, float b) {
    return (unsigned)f2bf(a) | ((unsigned)f2bf(b) << 16);
}
// tanh-form GELU (max |err| ~3e-4 vs erf form, << bf16 quantization)
__device__ __forceinline__ float gelu_tanh(float v) {
    const float z = 0.7978845608028654f * fmaf(0.044715f * v, v * v, v);
    const float e = __expf(2.f * z);
    const float th = fmaf(-2.f, __builtin_amdgcn_rcpf(1.f + e), 1.f);
    return 0.5f * v * (1.f + th);
}

// ---------------------------------------------------------------------------
// prep_embed_k: blocks [0,20000) = embed+PE+LN1; [20000,20192) = weight cvt;
// [20192,20832) = Pt transpose.  (merged: both independent of each other)
// ---------------------------------------------------------------------------
__global__ __launch_bounds__(256) void prep_embed_k(
    const float* __restrict__ x, const float* __restrict__ ew, const float* __restrict__ eb,
    const float* __restrict__ g1, const float* __restrict__ bb1,
    unsigned short* __restrict__ xeb, unsigned short* __restrict__ hnb,
    const float* __restrict__ wq, const float* __restrict__ wk, const float* __restrict__ wv,
    const float* __restrict__ wo, const float* __restrict__ w1, const float* __restrict__ w2,
    unsigned short* __restrict__ wqb, unsigned short* __restrict__ wkb, unsigned short* __restrict__ wvb,
    unsigned short* __restrict__ wob, unsigned short* __restrict__ w1b, unsigned short* __restrict__ w2b,
    const float* __restrict__ pK, const float* __restrict__ pV, unsigned short* __restrict__ Pt)
{
    __shared__ __align__(16) char lds[16384];
    const int t = threadIdx.x;
    const int bid = blockIdx.x;

    if (bid < 20000) {
        // ---- embed + PE + LN1 ----
        const int r = bid * 4 + (t >> 6);
        const int lane = t & 63;
        const int n = r % N_;
        const float xv = x[r];
        const float ang = (float)n * expf((float)lane * -0.14391156829962788f);
        float sv, cv; sincosf(ang, &sv, &cv);
        const int d0 = 2 * lane;
        float e0 = xv * ew[d0]     + eb[d0]     + sv;
        float e1 = xv * ew[d0 + 1] + eb[d0 + 1] + cv;
        float sum = e0 + e1, sq = e0 * e0 + e1 * e1;
        #pragma unroll
        for (int off = 32; off; off >>= 1) { sum += __shfl_xor(sum, off); sq += __shfl_xor(sq, off); }
        const float mu = sum * (1.f / 128.f);
        const float var = sq * (1.f / 128.f) - mu * mu;
        const float rs = rsqrtf(var + 1e-5f);
        const size_t base = (size_t)r * D_ + d0;
        *(unsigned*)&xeb[base] = pack2(e0, e1);
        *(unsigned*)&hnb[base] = pack2((e0 - mu) * rs * g1[d0] + bb1[d0],
                                       (e1 - mu) * rs * g1[d0 + 1] + bb1[d0 + 1]);
        return;
    }

    const int flat = bid - 20000;
    if (flat < 192) {
        const int by = flat / 32, bx = flat % 32;
        const float* s; unsigned short* d; int sz;
        switch (by) {
            case 0: s = wq; d = wqb; sz = 16384; break;
            case 1: s = wk; d = wkb; sz = 16384; break;
            case 2: s = wv; d = wvb; sz = 16384; break;
            case 3: s = wo; d = wob; sz = 16384; break;
            case 4: s = w1; d = w1b; sz = 65536; break;
            default: s = w2; d = w2b; sz = 65536; break;
        }
        const int idx = (bx * 256 + t) * 8;
        if (idx >= sz) return;
        float4 a = *(const float4*)(s + idx);
        float4 b = *(const float4*)(s + idx + 4);
        uint4 p;
        p.x = pack2(a.x, a.y); p.y = pack2(a.z, a.w);
        p.z = pack2(b.x, b.y); p.w = pack2(b.z, b.w);
        *(uint4*)(d + idx) = p;
        return;
    }

    // ---- ptt part ----
    const int f = flat - 192;
    const int bx = f % 160, rest = f / 160;
    const int n0 = bx * 64, k0 = (rest & 1) * 128, which = rest >> 1;
    const float* P = which ? pV : pK;
    {
        const int nl = t >> 2, cc = t & 3;
        const int n = n0 + nl;
        uint4 v[4] = {};
        if (n < N_) {
            const float4* src = (const float4*)(P + (size_t)n * K_ + k0 + cc * 32);
            #pragma unroll
            for (int j = 0; j < 4; ++j) {
                float4 a = src[2 * j], b = src[2 * j + 1];
                uint4 p; p.x = pack2(a.x, a.y); p.y = pack2(a.z, a.w);
                p.z = pack2(b.x, b.y); p.w = pack2(b.z, b.w);
                v[j] = p;
            }
        }
        #pragma unroll
        for (int j = 0; j < 4; ++j) {
            int ch = (cc * 4 + j) ^ (nl & 15);
            *(uint4*)(lds + nl * 256 + ch * 16) = v[j];
        }
    }
    __syncthreads();
    {
        const int ebb = t >> 3, nb = t & 7;
        unsigned short r0_[8], r1_[8], r2_[8], r3_[8];
        #pragma unroll
        for (int i = 0; i < 8; ++i) {
            int n = nb * 8 + i;
            int byte_ = n * 256 + (((ebb >> 1) ^ (n & 15)) << 4) + ((ebb & 1) << 3);
            uint2 dv = *(const uint2*)(lds + byte_);
            r0_[i] = (unsigned short)(dv.x & 0xffff); r1_[i] = (unsigned short)(dv.x >> 16);
            r2_[i] = (unsigned short)(dv.y & 0xffff); r3_[i] = (unsigned short)(dv.y >> 16);
        }
        size_t dbase = ((size_t)which * 256 + k0 + ebb * 4) * NPAD + n0 + nb * 8;
        *(uint4*)&Pt[dbase]            = *(uint4*)r0_;
        *(uint4*)&Pt[dbase + NPAD]     = *(uint4*)r1_;
        *(uint4*)&Pt[dbase + 2 * NPAD] = *(uint4*)r2_;
        *(uint4*)&Pt[dbase + 3 * NPAD] = *(uint4*)r3_;
    }
}

// ---------------------------------------------------------------------------
// hntq_k: blocks [0,1280) = hnT transpose; [1280,1905) = Q GEMM (hn@wq.T)
// ---------------------------------------------------------------------------
__global__ __launch_bounds__(256) void hntq_k(
    const unsigned short* __restrict__ hn, unsigned short* __restrict__ hnT,
    const unsigned short* __restrict__ wqb, unsigned short* __restrict__ qb)
{
    __shared__ __align__(16) char lds[16384];
    const int t = threadIdx.x;
    const int bid = blockIdx.x;

    if (bid < 1280) {
        // ---- hnT transpose ----
        const int n0 = (bid % 160) * 64, b = bid / 160;
        {
            const int nl = t >> 2, cc = t & 3;
            const int n = n0 + nl;
            uint4 v[4] = {};
            if (n < N_) {
                const uint4* src = (const uint4*)(hn + ((size_t)(b * N_ + n)) * D_ + cc * 32);
                #pragma unroll
                for (int j = 0; j < 4; ++j) v[j] = src[j];
            }
            #pragma unroll
            for (int j = 0; j < 4; ++j) {
                int ch = (cc * 4 + j) ^ (nl & 15);
                *(uint4*)(lds + nl * 256 + ch * 16) = v[j];
            }
        }
        __syncthreads();
        {
            const int ebb = t >> 3, nb = t & 7;
            unsigned short r0_[8], r1_[8], r2_[8], r3_[8];
            #pragma unroll
            for (int i = 0; i < 8; ++i) {
                int n = nb * 8 + i;
                int byte_ = n * 256 + (((ebb >> 1) ^ (n & 15)) << 4) + ((ebb & 1) << 3);
                uint2 dv = *(const uint2*)(lds + byte_);
                r0_[i] = (unsigned short)(dv.x & 0xffff); r1_[i] = (unsigned short)(dv.x >> 16);
                r2_[i] = (unsigned short)(dv.y & 0xffff); r3_[i] = (unsigned short)(dv.y >> 16);
            }
            size_t dbase = ((size_t)b * 128 + ebb * 4) * NPAD + n0 + nb * 8;
            *(uint4*)&hnT[dbase]            = *(uint4*)r0_;
            *(uint4*)&hnT[dbase + NPAD]     = *(uint4*)r1_;
            *(uint4*)&hnT[dbase + 2 * NPAD] = *(uint4*)r2_;
            *(uint4*)&hnT[dbase + 3 * NPAD] = *(uint4*)r3_;
        }
        return;
    }

    // ---- Q GEMM (128x128 tile, BK=32, NSTEP=4) ----
    const int bx = bid - 1280;
    const unsigned short* Ag = hn + (size_t)bx * 128 * 128;
    const unsigned short* Wg = wqb;
    const size_t cbase = (size_t)bx * 16384;

    const int srow = t >> 1, hib = 2 * (t & 1);
    const unsigned short* aptr = Ag + (size_t)srow * 128 + hib * 8;
    const unsigned short* wptr = Wg + (size_t)srow * 128 + hib * 8;
    const int swz = (srow >> 1) & 3;
    char* la0 = lds + srow * 64 + ((hib ^ swz) << 4);
    char* la1 = lds + srow * 64 + (((hib + 1) ^ swz) << 4);
    char* lw0 = la0 + 8192;
    char* lw1 = la1 + 8192;

    const int w = t >> 6, l = t & 63;
    const int g = l >> 4;
    const int wrow = (w & 1) * 64, wcol = (w >> 1) * 64;
    int offA[4], offW[4];
    #pragma unroll
    for (int mi = 0; mi < 4; ++mi) {
        int ra = wrow + mi * 16 + (l & 15);
        offA[mi] = ra * 64 + (((l >> 4) ^ ((ra >> 1) & 3)) << 4);
        int rw = wcol + mi * 16 + (l & 15);
        offW[mi] = 8192 + rw * 64 + (((l >> 4) ^ ((rw >> 1) & 3)) << 4);
    }

    f32x4 acc[4][4] = {};
    for (int s = 0; s < 4; ++s) {
        uint4 va0 = *(const uint4*)(aptr);
        uint4 va1 = *(const uint4*)(aptr + 8);
        uint4 vw0 = *(const uint4*)(wptr);
        uint4 vw1 = *(const uint4*)(wptr + 8);
        aptr += 32; wptr += 32;
        __syncthreads();
        *(uint4*)la0 = va0; *(uint4*)la1 = va1;
        *(uint4*)lw0 = vw0; *(uint4*)lw1 = vw1;
        __syncthreads();
        bf16x8 af[4], bfr[4];
        #pragma unroll
        for (int mi = 0; mi < 4; ++mi) {
            af[mi] = *(const bf16x8*)(lds + offA[mi]);
            bfr[mi] = *(const bf16x8*)(lds + offW[mi]);
        }
        #pragma unroll
        for (int mi = 0; mi < 4; ++mi)
            #pragma unroll
            for (int ni = 0; ni < 4; ++ni)
                acc[mi][ni] = __builtin_amdgcn_mfma_f32_16x16x32_bf16(af[mi], bfr[ni], acc[mi][ni], 0, 0, 0);
    }

    const int lrb = wrow + (g << 2);
    const int lcb = wcol + (l & 15);
    #pragma unroll
    for (int mi = 0; mi < 4; ++mi)
        #pragma unroll
        for (int ni = 0; ni < 4; ++ni) {
            const int lc = lcb + ni * 16;
            #pragma unroll
            for (int r = 0; r < 4; ++r) {
                const int lr = lrb + mi * 16 + r;
                qb[cbase + (size_t)lr * 128 + lc] = f2bf(acc[mi][ni][r]);
            }
        }
}

// ---------------------------------------------------------------------------
// MFMA GEMM. Modes: M_PROJ (split-K 16), M_SMALL.
// ---------------------------------------------------------------------------
enum { M_PROJ = 1, M_SMALL = 2 };

template<int MODE>
__global__ __launch_bounds__(256) void mgemm_k(
    const unsigned short* __restrict__ Abase, const unsigned short* __restrict__ Wbase,
    const unsigned short* __restrict__ Walt,
    float* __restrict__ Cf, unsigned short* __restrict__ Cb)
{
    constexpr int NSTEP = (MODE == M_PROJ) ? 20 : 4;
    constexpr int SA = (MODE == M_PROJ) ? NPAD : 128;
    constexpr int SB = SA;

    __shared__ __align__(16) char lds[16384];

    const int t = threadIdx.x;
    const int bx = blockIdx.x, bz = blockIdx.z;

    const unsigned short* Ag; const unsigned short* Wg; size_t cbase;
    if (MODE == M_PROJ) {
        const int b = (bz >> 4) & 7, chunk = bz & 15, which = bz >> 7;
        Ag = Abase + (size_t)which * 256 * NPAD + (size_t)bx * 128 * NPAD + chunk * 640;
        Wg = Wbase + (size_t)b * 128 * NPAD + chunk * 640;
        cbase = (size_t)bz * 32768 + (size_t)bx * 16384;
    } else {
        Ag = Abase + (size_t)bz * 2048 * 128 + (size_t)bx * 128 * 128;
        Wg = bz ? Walt : Wbase;
        cbase = (size_t)bz * 262144 + (size_t)bx * 16384;
    }

    const int srow = t >> 1, hib = 2 * (t & 1);
    const unsigned short* aptr = Ag + (size_t)srow * SA + hib * 8;
    const unsigned short* wptr = Wg + (size_t)srow * SB + hib * 8;
    const int swz = (srow >> 1) & 3;
    char* la0 = lds + srow * 64 + ((hib ^ swz) << 4);
    char* la1 = lds + srow * 64 + (((hib + 1) ^ swz) << 4);
    char* lw0 = la0 + 8192;
    char* lw1 = la1 + 8192;

    const int w = t >> 6, l = t & 63;
    const int g = l >> 4;
    const int wrow = (w & 1) * 64, wcol = (w >> 1) * 64;
    int offA[4], offW[4];
    #pragma unroll
    for (int mi = 0; mi < 4; ++mi) {
        int ra = wrow + mi * 16 + (l & 15);
        offA[mi] = ra * 64 + (((l >> 4) ^ ((ra >> 1) & 3)) << 4);
        int rw = wcol + mi * 16 + (l & 15);
        offW[mi] = 8192 + rw * 64 + (((l >> 4) ^ ((rw >> 1) & 3)) << 4);
    }

    f32x4 acc[4][4] = {};

    for (int s = 0; s < NSTEP; ++s) {
        uint4 va0 = *(const uint4*)(aptr);
        uint4 va1 = *(const uint4*)(aptr + 8);
        uint4 vw0 = *(const uint4*)(wptr);
        uint4 vw1 = *(const uint4*)(wptr + 8);
        aptr += 32; wptr += 32;
        __syncthreads();
        *(uint4*)la0 = va0; *(uint4*)la1 = va1;
        *(uint4*)lw0 = vw0; *(uint4*)lw1 = vw1;
        __syncthreads();
        bf16x8 af[4], bfr[4];
        #pragma unroll
        for (int mi = 0; mi < 4; ++mi) {
            af[mi] = *(const bf16x8*)(lds + offA[mi]);
            bfr[mi] = *(const bf16x8*)(lds + offW[mi]);
        }
        #pragma unroll
        for (int mi = 0; mi < 4; ++mi)
            #pragma unroll
            for (int ni = 0; ni < 4; ++ni)
                acc[mi][ni] = __builtin_amdgcn_mfma_f32_16x16x32_bf16(af[mi], bfr[ni], acc[mi][ni], 0, 0, 0);
    }

    const int lrb = wrow + (g << 2);
    const int lcb = wcol + (l & 15);
    #pragma unroll
    for (int mi = 0; mi < 4; ++mi) {
        #pragma unroll
        for (int ni = 0; ni < 4; ++ni) {
            const int lc = lcb + ni * 16;
            #pragma unroll
            for (int r = 0; r < 4; ++r) {
                const int lr = lrb + mi * 16 + r;
                const float v = acc[mi][ni][r];
                const size_t ci = cbase + (size_t)lr * 128 + lc;
                if (MODE == M_SMALL) Cb[ci] = f2bf(v); else Cf[ci] = v;
            }
        }
    }
}

// ---------------------------------------------------------------------------
// reduce split-K partials (16 chunks) -> lowKV bf16
// ---------------------------------------------------------------------------
__global__ __launch_bounds__(256) void reduce_k(
    const float* __restrict__ partials, unsigned short* __restrict__ lowKV)
{
    const int gid = blockIdx.x * 256 + threadIdx.x;
    const int wb = gid >> 15, r = gid & 32767;
    const float* p = partials + (size_t)wb * 16 * 32768 + r;
    float s = 0.f;
    #pragma unroll
    for (int c = 0; c < 16; ++c) s += p[c * 32768];
    lowKV[gid] = f2bf(s);
}

// ---------------------------------------------------------------------------
// Fused WO + residual + LN2 + FFN + residual + row-sum -> st.  (v3: wave-local)
// Each of the 4 waves owns 16 complete rows: WO (swapped, 8 ni x 4 ks),
// LN stats via shfl only, LN2 rewrites the wave's own 4KB LDS slice, FFN
// hc-loop uses a wave-local 4KB hidden slice. ZERO __syncthreads.
// LDS = 4x4KB (A/A2) + 4x4KB (H) = 32KB exactly -> 5 blocks/CU by LDS.
// xe' never hits HBM; its row-sum (tot) redistributed at the end via __shfl.
// ---------------------------------------------------------------------------
__global__ __launch_bounds__(256) void wo_ffn_k(
    const unsigned short* __restrict__ attn_out, const unsigned short* __restrict__ wob,
    const float* __restrict__ wo_bias, const unsigned short* __restrict__ xeb,
    const float* __restrict__ lng, const float* __restrict__ lnb,
    const unsigned short* __restrict__ w1b, const float* __restrict__ b1,
    const unsigned short* __restrict__ w2b, const float* __restrict__ b2,
    float* __restrict__ st)
{
    __shared__ __align__(16) char lds[32768];
    const int t = threadIdx.x;
    const int w = t >> 6, l = t & 63;
    const int g = l >> 4, ql = l & 15;
    const int r0 = blockIdx.x * 64 + w * 16;     // wave's 16 global rows
    char* SA = lds + w * 4096;                   // [16][256B] attn-out, then LN2 out
    char* SH = lds + 16384 + w * 4096;           // [16][256B] hidden chunk

    // ---- stage attn-out (wave-local, 16 rows) ----
    {
        const int rr = l >> 2, cc = l & 3;
        #pragma unroll
        for (int j = 0; j < 4; ++j) {
            const int ch = cc * 4 + j;
            const uint4 v = *(const uint4*)(attn_out + (size_t)(r0 + rr) * 128 + ch * 8);
            *(uint4*)(SA + rr * 256 + ((ch ^ rr) << 4)) = v;
        }
    }

    // ---- WO GEMM (swapped): wacc[ni] = C[cols ni*16+g*4+j][row ql] ----
    f32x4 wacc[8] = {};
    #pragma unroll
    for (int ks = 0; ks < 4; ++ks) {
        const int e0 = ks * 32 + g * 8;
        const bf16x8 af = *(const bf16x8*)(SA + ql * 256 + (((e0 >> 3) ^ ql) << 4));
        #pragma unroll
        for (int ni = 0; ni < 8; ++ni) {
            const bf16x8 wf = *(const bf16x8*)(wob + (size_t)(ni * 16 + ql) * 128 + e0);
            wacc[ni] = __builtin_amdgcn_mfma_f32_16x16x32_bf16(wf, af, wacc[ni], 0, 0, 0);
        }
    }

    // ---- bias + residual + row stats (wave-only shfl) ----
    float rsum = 0.f, rsq = 0.f;
    #pragma unroll
    for (int ni = 0; ni < 8; ++ni) {
        const int col0 = ni * 16 + g * 4;
        const float4 wb4 = *(const float4*)&wo_bias[col0];
        const uint2 xr = *(const uint2*)&xeb[(size_t)(r0 + ql) * 128 + col0];
        float xv[4];
        xv[0] = bf2f((unsigned short)(xr.x & 0xffff)); xv[1] = bf2f((unsigned short)(xr.x >> 16));
        xv[2] = bf2f((unsigned short)(xr.y & 0xffff)); xv[3] = bf2f((unsigned short)(xr.y >> 16));
        const float wb_[4] = {wb4.x, wb4.y, wb4.z, wb4.w};
        #pragma unroll
        for (int j = 0; j < 4; ++j) {
            const float v = wacc[ni][j] + wb_[j] + xv[j];
            wacc[ni][j] = v;
            rsum += v;
            rsq += v * v;
        }
    }
    rsum += __shfl_xor(rsum, 16); rsum += __shfl_xor(rsum, 32);
    rsq  += __shfl_xor(rsq, 16);  rsq  += __shfl_xor(rsq, 32);
    const float tot = rsum;                       // xe' row-sum for row ql
    const float mu = tot * (1.f / 128.f);
    const float var = rsq * (1.f / 128.f) - mu * mu;
    const float rstd = rsqrtf(var + 1e-5f);

    // ---- LN apply -> SA (overwrite own slice) ----
    #pragma unroll
    for (int ni = 0; ni < 8; ++ni) {
        const int col0 = ni * 16 + g * 4;
        const float4 lg4 = *(const float4*)&lng[col0];
        const float4 lb4 = *(const float4*)&lnb[col0];
        const float lg_[4] = {lg4.x, lg4.y, lg4.z, lg4.w};
        const float lb_[4] = {lb4.x, lb4.y, lb4.z, lb4.w};
        float h_[4];
        #pragma unroll
        for (int j = 0; j < 4; ++j)
            h_[j] = (wacc[ni][j] - mu) * rstd * lg_[j] + lb_[j];
        uint2 pk;
        pk.x = pack2(h_[0], h_[1]);
        pk.y = pack2(h_[2], h_[3]);
        const int chunk = col0 >> 3;
        const int sub = (col0 & 4) << 1;
        *(uint2*)(SA + ql * 256 + ((chunk ^ ql) << 4) + sub) = pk;
    }

    // ---- FFN (4 hidden chunks of 128, wave-local) ----
    f32x4 accF[8] = {};
    #pragma unroll
    for (int hc = 0; hc < 4; ++hc) {
        // stage1 (swapped): hacc[ni] = hidden cols hc*128+ni*16+g*4+j, row ql
        f32x4 hacc[8] = {};
        #pragma unroll
        for (int ks = 0; ks < 4; ++ks) {
            const int e0 = ks * 32 + g * 8;
            const bf16x8 hf = *(const bf16x8*)(SA + ql * 256 + (((e0 >> 3) ^ ql) << 4));
            #pragma unroll
            for (int ni = 0; ni < 8; ++ni) {
                const bf16x8 wf1 = *(const bf16x8*)(w1b + (size_t)(hc * 128 + ni * 16 + ql) * 128 + e0);
                hacc[ni] = __builtin_amdgcn_mfma_f32_16x16x32_bf16(wf1, hf, hacc[ni], 0, 0, 0);
            }
        }
        // bias + gelu + packed store to SH
        #pragma unroll
        for (int ni = 0; ni < 8; ++ni) {
            const int colb = ni * 16 + g * 4;
            const float4 bb = *(const float4*)&b1[hc * 128 + colb];
            uint2 pk;
            pk.x = pack2(gelu_tanh(hacc[ni][0] + bb.x), gelu_tanh(hacc[ni][1] + bb.y));
            pk.y = pack2(gelu_tanh(hacc[ni][2] + bb.z), gelu_tanh(hacc[ni][3] + bb.w));
            const int chb = colb >> 3;
            const int sub = (colb & 4) << 1;
            *(uint2*)(SH + ql * 256 + ((chb ^ ql) << 4) + sub) = pk;
        }
        // stage2 (standard): accF[ni] rows g*4+r, cols ni*16+ql
        #pragma unroll
        for (int ks = 0; ks < 4; ++ks) {
            const int e0 = ks * 32 + g * 8;
            const bf16x8 ah = *(const bf16x8*)(SH + ql * 256 + (((e0 >> 3) ^ ql) << 4));
            #pragma unroll
            for (int ni = 0; ni < 8; ++ni) {
                const bf16x8 wf2 = *(const bf16x8*)(w2b + (size_t)(ni * 16 + ql) * 512 + hc * 128 + e0);
                accF[ni] = __builtin_amdgcn_mfma_f32_16x16x32_bf16(ah, wf2, accF[ni], 0, 0, 0);
            }
        }
    }

    // ---- final row-sum: st = sum(ffn + b2) + tot ----
    float rF[4] = {0.f, 0.f, 0.f, 0.f};
    #pragma unroll
    for (int ni = 0; ni < 8; ++ni) {
        const float b2c = b2[ni * 16 + ql];
        #pragma unroll
        for (int r = 0; r < 4; ++r) rF[r] += accF[ni][r] + b2c;
    }
    #pragma unroll
    for (int r = 0; r < 4; ++r) {
        rF[r] += __shfl_xor(rF[r], 1);
        rF[r] += __shfl_xor(rF[r], 2);
        rF[r] += __shfl_xor(rF[r], 4);
        rF[r] += __shfl_xor(rF[r], 8);
    }
    float totr[4];
    #pragma unroll
    for (int r = 0; r < 4; ++r) totr[r] = __shfl(tot, g * 4 + r);   // all lanes participate
    if (ql == 0) {
        #pragma unroll
        for (int r = 0; r < 4; ++r) {
            const int grow = r0 + g * 4 + r;
            const int bidx = grow / N_;
            const int n = grow - bidx * N_;
            st[(size_t)n * 8 + bidx] = rF[r] + totr[r];
        }
    }
}

// ---------------------------------------------------------------------------
// MFMA attention (K_lds swizzle (r&3)<<4 within 64B rows).
// ---------------------------------------------------------------------------
__global__ __launch_bounds__(256) void attn_mfma_k(
    const unsigned short* __restrict__ q, const unsigned short* __restrict__ kv,
    unsigned short* __restrict__ outp)
{
    __shared__ __align__(16) char lds[65536];
    const int t = threadIdx.x;
    const int w = t >> 6, l = t & 63;
    const int g = l >> 4, ql = l & 15;
    const int h = blockIdx.y, b = blockIdx.z;
    const int q0 = blockIdx.x * 256;
    const float SC = 0.17677669529663687f;   // 1/sqrt(32)

    #pragma unroll
    for (int i = 0; i < 4; ++i) {
        const int r = (t >> 2) + 64 * i;
        const uint4 v = *(const uint4*)(kv + ((size_t)(b * 256 + r) * 128 + h * 32) + (t & 3) * 8);
        *(uint4*)(lds + r * 64 + (((t & 3) * 16) ^ ((r & 3) << 4))) = v;
    }
    {
        const int kp = t & 127, dhalf = t >> 7;
        const unsigned short* vsrc = kv + 262144 + ((size_t)(b * 256 + 2 * kp) * 128 + h * 32 + 16 * dhalf);
        uint4 a0 = *(const uint4*)(vsrc);
        uint4 a1 = *(const uint4*)(vsrc + 8);
        uint4 c0 = *(const uint4*)(vsrc + 128);
        uint4 c1 = *(const uint4*)(vsrc + 136);
        const unsigned short* pa0 = (const unsigned short*)&a0;
        const unsigned short* pa1 = (const unsigned short*)&a1;
        const unsigned short* pc0 = (const unsigned short*)&c0;
        const unsigned short* pc1 = (const unsigned short*)&c1;
        #pragma unroll
        for (int j = 0; j < 8; ++j) {
            const int row = 16 * dhalf + j;
            unsigned u = (unsigned)pa0[j] | ((unsigned)pc0[j] << 16);
            *(unsigned*)(lds + 16384 + row * 512 + ((4 * kp) ^ ((row & 7) << 4))) = u;
        }
        #pragma unroll
        for (int j = 0; j < 8; ++j) {
            const int row = 16 * dhalf + 8 + j;
            unsigned u = (unsigned)pa1[j] | ((unsigned)pc1[j] << 16);
            *(unsigned*)(lds + 16384 + row * 512 + ((4 * kp) ^ ((row & 7) << 4))) = u;
        }
    }
    bf16x8 qfr[4];
    #pragma unroll
    for (int qf = 0; qf < 4; ++qf) {
        int n = q0 + w * 64 + qf * 16 + ql;
        if (n >= N_) n = N_ - 1;
        qfr[qf] = *(const bf16x8*)(q + ((size_t)(b * N_ + n) * 128 + h * 32 + g * 8));
    }
    __syncthreads();

    char* Pw = lds + 32768 + w * 8192;
    f32x4 oacc[2][4] = {};
    float m_run[4], l_run[4];
    #pragma unroll
    for (int qf = 0; qf < 4; ++qf) { m_run[qf] = -1e30f; l_run[qf] = 0.f; }

    for (int kt = 0; kt < 4; ++kt) {
        const int kb = kt * 64;
        bf16x8 kfr[4];
        #pragma unroll
        for (int kf = 0; kf < 4; ++kf) {
            const int r = kb + kf * 16 + ql;
            kfr[kf] = *(const bf16x8*)(lds + r * 64 + ((g * 16) ^ ((r & 3) << 4)));
        }
        f32x4 s_[4][4];
        #pragma unroll
        for (int kf = 0; kf < 4; ++kf)
            #pragma unroll
            for (int qf = 0; qf < 4; ++qf) {
                f32x4 z = {0.f, 0.f, 0.f, 0.f};
                s_[kf][qf] = __builtin_amdgcn_mfma_f32_16x16x32_bf16(kfr[kf], qfr[qf], z, 0, 0, 0);
            }
        #pragma unroll
        for (int qf = 0; qf < 4; ++qf) {
            float mx = -1e30f;
            #pragma unroll
            for (int kf = 0; kf < 4; ++kf)
                #pragma unroll
                for (int r = 0; r < 4; ++r) mx = fmaxf(mx, s_[kf][qf][r]);
            mx = fmaxf(mx, __shfl_xor(mx, 16));
            mx = fmaxf(mx, __shfl_xor(mx, 32));
            mx *= SC;
            if (mx > m_run[qf]) {
                const float corr = __expf(m_run[qf] - mx);
                l_run[qf] *= corr;
                #pragma unroll
                for (int df = 0; df < 2; ++df) {
                    oacc[df][qf][0] *= corr; oacc[df][qf][1] *= corr;
                    oacc[df][qf][2] *= corr; oacc[df][qf][3] *= corr;
                }
                m_run[qf] = mx;
            }
            float p_[4][4]; float ssum = 0.f;
            #pragma unroll
            for (int kf = 0; kf < 4; ++kf)
                #pragma unroll
                for (int r = 0; r < 4; ++r) {
                    const float pv = __expf(s_[kf][qf][r] * SC - m_run[qf]);
                    p_[kf][r] = pv; ssum += pv;
                }
            ssum += __shfl_xor(ssum, 16);
            ssum += __shfl_xor(ssum, 32);
            l_run[qf] += ssum;
            const int qrow = qf * 16 + ql;
            #pragma unroll
            for (int kf = 0; kf < 4; ++kf) {
                uint2 pk;
                pk.x = pack2(p_[kf][0], p_[kf][1]);
                pk.y = pack2(p_[kf][2], p_[kf][3]);
                *(uint2*)(Pw + qrow * 128 + ((kf * 32 + g * 8) ^ ((qrow & 7) << 4))) = pk;
            }
        }
        asm volatile("s_waitcnt lgkmcnt(0)" ::: "memory");
        __builtin_amdgcn_sched_barrier(0);
        #pragma unroll
        for (int ks = 0; ks < 2; ++ks) {
            bf16x8 vt_[2];
            #pragma unroll
            for (int df = 0; df < 2; ++df) {
                const int row = df * 16 + ql;
                vt_[df] = *(const bf16x8*)(lds + 16384 + row * 512 +
                           ((kb * 2 + ks * 64 + g * 16) ^ ((row & 7) << 4)));
            }
            #pragma unroll
            for (int qf = 0; qf < 4; ++qf) {
                const int qrow = qf * 16 + ql;
                bf16x8 pf = *(const bf16x8*)(Pw + qrow * 128 + ((ks * 64 + g * 16) ^ ((qrow & 7) << 4)));
                #pragma unroll
                for (int df = 0; df < 2; ++df)
                    oacc[df][qf] = __builtin_amdgcn_mfma_f32_16x16x32_bf16(vt_[df], pf, oacc[df][qf], 0, 0, 0);
            }
        }
        asm volatile("s_waitcnt lgkmcnt(0)" ::: "memory");
        __builtin_amdgcn_sched_barrier(0);
    }

    float inv_[4];
    #pragma unroll
    for (int qf = 0; qf < 4; ++qf) inv_[qf] = 1.f / l_run[qf];
    #pragma unroll
    for (int qf = 0; qf < 4; ++qf) {
        const int qrow = qf * 16 + ql;
        #pragma unroll
        for (int df = 0; df < 2; ++df) {
            const unsigned lo = pack2(oacc[df][qf][0] * inv_[qf], oacc[df][qf][1] * inv_[qf]);
            const unsigned hi = pack2(oacc[df][qf][2] * inv_[qf], oacc[df][qf][3] * inv_[qf]);
            *(unsigned*)(Pw + qrow * 64 + ((df * 32 + g * 8) ^ ((qrow & 3) << 4))) = lo;
            *(unsigned*)(Pw + qrow * 64 + ((df * 32 + g * 8 + 4) ^ ((qrow & 3) << 4))) = hi;
        }
    }
    asm volatile("s_waitcnt lgkmcnt(0)" ::: "memory");
    __builtin_amdgcn_sched_barrier(0);
    #pragma unroll
    for (int pp = 0; pp < 4; ++pp) {
        const int qrow = pp * 16 + (l >> 2), c = l & 3;
        const uint4 v = *(const uint4*)(Pw + qrow * 64 + ((c * 16) ^ ((qrow & 3) << 4)));
        const int n = q0 + w * 64 + qrow;
        if (n < N_)
            *(uint4*)(outp + ((size_t)(b * N_ + n) * 128 + h * 32 + c * 8)) = v;
    }
}

// ---------------------------------------------------------------------------
// fc2_k + combine (see R7)
// ---------------------------------------------------------------------------
__global__ __launch_bounds__(256) void fc2_k(
    const float* __restrict__ st, const float* __restrict__ fcw,
    float* __restrict__ part)
{
    __shared__ float s_lds[16000];   // [2000][8]
    const int t = threadIdx.x;
    const int m0 = blockIdx.x * 64;
    const int n0 = blockIdx.y * 2000;

    const float4* src = (const float4*)(st + (size_t)n0 * 8);
    #pragma unroll 4
    for (int i = t; i < 4000; i += 256)
        ((float4*)s_lds)[i] = src[i];
    __syncthreads();

    const int mloc = t >> 2, q = t & 3;
    const int m = m0 + mloc;
    float acc[8] = {};
    if (m < M_) {
        const float* wrow = fcw + (size_t)m * N_ + n0;
        for (int k = 0; k < 125; ++k) {
            const int nn = q * 4 + k * 16;
            const float4 wv = *(const float4*)(wrow + nn);
            const float wl[4] = {wv.x, wv.y, wv.z, wv.w};
            #pragma unroll
            for (int j = 0; j < 4; ++j) {
                const float4 sa = *(const float4*)(s_lds + (nn + j) * 8);
                const float4 sb = *(const float4*)(s_lds + (nn + j) * 8 + 4);
                acc[0] = fmaf(wl[j], sa.x, acc[0]); acc[1] = fmaf(wl[j], sa.y, acc[1]);
                acc[2] = fmaf(wl[j], sa.z, acc[2]); acc[3] = fmaf(wl[j], sa.w, acc[3]);
                acc[4] = fmaf(wl[j], sb.x, acc[4]); acc[5] = fmaf(wl[j], sb.y, acc[5]);
                acc[6] = fmaf(wl[j], sb.z, acc[6]); acc[7] = fmaf(wl[j], sb.w, acc[7]);
            }
        }
    }
    #pragma unroll
    for (int j = 0; j < 8; ++j) {
        acc[j] += __shfl_xor(acc[j], 1);
        acc[j] += __shfl_xor(acc[j], 2);
    }
    if (q == 0 && m < M_) {
        float* pb = part + (size_t)blockIdx.y * 40000 + m;
        #pragma unroll
        for (int bb = 0; bb < 8; ++bb) pb[bb * 5000] = acc[bb];
    }
}

__global__ __launch_bounds__(256) void fc_combine_k(
    const float* __restrict__ part, const float* __restrict__ fcb,
    float* __restrict__ out)
{
    const int i = blockIdx.x * 256 + threadIdx.x;
    if (i >= 40000) return;
    float s = 0.f;
    #pragma unroll
    for (int c = 0; c < 5; ++c) s += part[c * 40000 + i];
    const int m = i % 5000;
    out[i] = s + 128.f * fcb[m];
}

// ---------------------------------------------------------------------------
extern "C" void kernel_launch(void* const* d_in, const int* in_sizes, int n_in,
                              void* d_out, int out_size, void* d_ws, size_t ws_size,
                              hipStream_t stream)
{
    const float* x      = (const float*)d_in[0];
    const float* emb_w  = (const float*)d_in[1];
    const float* emb_b  = (const float*)d_in[2];
    const float* ln1_g  = (const float*)d_in[3];
    const float* ln1_b  = (const float*)d_in[4];
    const float* wq     = (const float*)d_in[5];
    const float* wk     = (const float*)d_in[6];
    const float* wv     = (const float*)d_in[7];
    const float* projk  = (const float*)d_in[8];
    const float* projv  = (const float*)d_in[9];
    const float* wo     = (const float*)d_in[10];
    const float* wo_b   = (const float*)d_in[11];
    const float* ln2_g  = (const float*)d_in[12];
    const float* ln2_b  = (const float*)d_in[13];
    const float* w1     = (const float*)d_in[14];
    const float* b1     = (const float*)d_in[15];
    const float* w2     = (const float*)d_in[16];
    const float* b2     = (const float*)d_in[17];
    const float* fcw    = (const float*)d_in[18];
    const float* fcb    = (const float*)d_in[19];
    float* out = (float*)d_out;

    char* W = (char*)d_ws;
    unsigned short* xeb      = (unsigned short*)W;                     // 20,480,000
    unsigned short* hnb      = (unsigned short*)(W + 40960000);        // 20,480,000
    char*           region   = W + 61440000;
    unsigned short* qb       = (unsigned short*)region;                // 20,480,000
    unsigned short* hnT      = (unsigned short*)(region + 20480000);   // 20,971,520
    unsigned short* Pt       = (unsigned short*)(region + 41451520);   // 10,485,760
    float*          partials = (float*)(region + 51937280);            // 33,554,432 (16 chunks)
    unsigned short* lowKV    = (unsigned short*)(W + 146931712);       // 1,048,576
    unsigned short* klowb    = (unsigned short*)(W + 147980288);       // [2][2048][128] bf16
    unsigned short* wqb      = (unsigned short*)(W + 150077440);
    unsigned short* wkb      = wqb + 16384;
    unsigned short* wvb      = wkb + 16384;
    unsigned short* wob      = wvb + 16384;
    unsigned short* w1b      = wob + 16384;
    unsigned short* w2b      = w1b + 65536;
    float*          st       = (float*)(W + 150470656);                // 320,000
    float*          fcpart   = (float*)(W + 150790656);                // 800,000

    prep_embed_k<<<20832, 256, 0, stream>>>(x, emb_w, emb_b, ln1_g, ln1_b, xeb, hnb,
                                            wq, wk, wv, wo, w1, w2,
                                            wqb, wkb, wvb, wob, w1b, w2b,
                                            projk, projv, Pt);
    hntq_k<<<1905, 256, 0, stream>>>(hnb, hnT, wqb, qb);
    mgemm_k<M_PROJ><<<dim3(2, 1, 256), 256, 0, stream>>>(Pt, hnT, nullptr, partials, nullptr);
    reduce_k<<<2048, 256, 0, stream>>>(partials, lowKV);
    mgemm_k<M_SMALL><<<dim3(16, 1, 2), 256, 0, stream>>>(lowKV, wkb, wvb, nullptr, klowb);
    attn_mfma_k<<<dim3(40, H_, B_), 256, 0, stream>>>(qb, klowb, hnb);
    wo_ffn_k<<<1250, 256, 0, stream>>>(hnb, wob, wo_b, xeb, ln2_g, ln2_b, w1b, b1, w2b, b2, st);
    fc2_k<<<dim3(79, 5), 256, 0, stream>>>(st, fcw, fcpart);
    fc_combine_k<<<157, 256, 0, stream>>>(fcpart, fcb, out);
}

// Round 12
// 314.157 us; speedup vs baseline: 1.2319x; 1.2319x over previous
//
#include <hip/hip_runtime.h>

constexpr int B_ = 8, N_ = 10000, D_ = 128, H_ = 4, K_ = 256, M_ = 5000, DFF_ = 512;
constexpr int NPAD = 10240;   // n padded to multiple of 32 for MFMA K-loop

typedef __attribute__((ext_vector_type(8))) short bf16x8;
typedef __attribute__((ext_vector_type(4))) float f32x4;

__device__ __forceinline__ float bf2f(unsigned short u) {
    unsigned x = ((unsigned)u) << 16; float f; __builtin_memcpy(&f, &x, 4); return f;
}
__device__ __forceinline__ unsigned short f2bf(float f) {
    unsigned x; __builtin_memcpy(&x, &f, 4);
    x = (x + 0x7fffu + ((x >> 16) & 1u)) >> 16;   // RNE
    return (unsigned short)x;
}
__device__ __forceinline__ unsigned pack2(float a, float b) {
    return (unsigned)f2bf(a) | ((unsigned)f2bf(b) << 16);
}
// tanh-form GELU (max |err| ~3e-4 vs erf form, << bf16 quantization)
__device__ __forceinline__ float gelu_tanh(float v) {
    const float z = 0.7978845608028654f * fmaf(0.044715f * v, v * v, v);
    const float e = __expf(2.f * z);
    const float th = fmaf(-2.f, __builtin_amdgcn_rcpf(1.f + e), 1.f);
    return 0.5f * v * (1.f + th);
}

// ---------------------------------------------------------------------------
// prep_embed_k: blocks [0,20000) = embed+PE+LN1; [20000,20192) = weight cvt;
// [20192,20832) = Pt transpose.
// ---------------------------------------------------------------------------
__global__ __launch_bounds__(256) void prep_embed_k(
    const float* __restrict__ x, const float* __restrict__ ew, const float* __restrict__ eb,
    const float* __restrict__ g1, const float* __restrict__ bb1,
    unsigned short* __restrict__ xeb, unsigned short* __restrict__ hnb,
    const float* __restrict__ wq, const float* __restrict__ wk, const float* __restrict__ wv,
    const float* __restrict__ wo, const float* __restrict__ w1, const float* __restrict__ w2,
    unsigned short* __restrict__ wqb, unsigned short* __restrict__ wkb, unsigned short* __restrict__ wvb,
    unsigned short* __restrict__ wob, unsigned short* __restrict__ w1b, unsigned short* __restrict__ w2b,
    const float* __restrict__ pK, const float* __restrict__ pV, unsigned short* __restrict__ Pt)
{
    __shared__ __align__(16) char lds[16384];
    const int t = threadIdx.x;
    const int bid = blockIdx.x;

    if (bid < 20000) {
        const int r = bid * 4 + (t >> 6);
        const int lane = t & 63;
        const int n = r % N_;
        const float xv = x[r];
        const float ang = (float)n * expf((float)lane * -0.14391156829962788f);
        float sv, cv; sincosf(ang, &sv, &cv);
        const int d0 = 2 * lane;
        float e0 = xv * ew[d0]     + eb[d0]     + sv;
        float e1 = xv * ew[d0 + 1] + eb[d0 + 1] + cv;
        float sum = e0 + e1, sq = e0 * e0 + e1 * e1;
        #pragma unroll
        for (int off = 32; off; off >>= 1) { sum += __shfl_xor(sum, off); sq += __shfl_xor(sq, off); }
        const float mu = sum * (1.f / 128.f);
        const float var = sq * (1.f / 128.f) - mu * mu;
        const float rs = rsqrtf(var + 1e-5f);
        const size_t base = (size_t)r * D_ + d0;
        *(unsigned*)&xeb[base] = pack2(e0, e1);
        *(unsigned*)&hnb[base] = pack2((e0 - mu) * rs * g1[d0] + bb1[d0],
                                       (e1 - mu) * rs * g1[d0 + 1] + bb1[d0 + 1]);
        return;
    }

    const int flat = bid - 20000;
    if (flat < 192) {
        const int by = flat / 32, bx = flat % 32;
        const float* s; unsigned short* d; int sz;
        switch (by) {
            case 0: s = wq; d = wqb; sz = 16384; break;
            case 1: s = wk; d = wkb; sz = 16384; break;
            case 2: s = wv; d = wvb; sz = 16384; break;
            case 3: s = wo; d = wob; sz = 16384; break;
            case 4: s = w1; d = w1b; sz = 65536; break;
            default: s = w2; d = w2b; sz = 65536; break;
        }
        const int idx = (bx * 256 + t) * 8;
        if (idx >= sz) return;
        float4 a = *(const float4*)(s + idx);
        float4 b = *(const float4*)(s + idx + 4);
        uint4 p;
        p.x = pack2(a.x, a.y); p.y = pack2(a.z, a.w);
        p.z = pack2(b.x, b.y); p.w = pack2(b.z, b.w);
        *(uint4*)(d + idx) = p;
        return;
    }

    // ---- ptt part ----
    const int f = flat - 192;
    const int bx = f % 160, rest = f / 160;
    const int n0 = bx * 64, k0 = (rest & 1) * 128, which = rest >> 1;
    const float* P = which ? pV : pK;
    {
        const int nl = t >> 2, cc = t & 3;
        const int n = n0 + nl;
        uint4 v[4] = {};
        if (n < N_) {
            const float4* src = (const float4*)(P + (size_t)n * K_ + k0 + cc * 32);
            #pragma unroll
            for (int j = 0; j < 4; ++j) {
                float4 a = src[2 * j], b = src[2 * j + 1];
                uint4 p; p.x = pack2(a.x, a.y); p.y = pack2(a.z, a.w);
                p.z = pack2(b.x, b.y); p.w = pack2(b.z, b.w);
                v[j] = p;
            }
        }
        #pragma unroll
        for (int j = 0; j < 4; ++j) {
            int ch = (cc * 4 + j) ^ (nl & 15);
            *(uint4*)(lds + nl * 256 + ch * 16) = v[j];
        }
    }
    __syncthreads();
    {
        const int ebb = t >> 3, nb = t & 7;
        unsigned short r0_[8], r1_[8], r2_[8], r3_[8];
        #pragma unroll
        for (int i = 0; i < 8; ++i) {
            int n = nb * 8 + i;
            int byte_ = n * 256 + (((ebb >> 1) ^ (n & 15)) << 4) + ((ebb & 1) << 3);
            uint2 dv = *(const uint2*)(lds + byte_);
            r0_[i] = (unsigned short)(dv.x & 0xffff); r1_[i] = (unsigned short)(dv.x >> 16);
            r2_[i] = (unsigned short)(dv.y & 0xffff); r3_[i] = (unsigned short)(dv.y >> 16);
        }
        size_t dbase = ((size_t)which * 256 + k0 + ebb * 4) * NPAD + n0 + nb * 8;
        *(uint4*)&Pt[dbase]            = *(uint4*)r0_;
        *(uint4*)&Pt[dbase + NPAD]     = *(uint4*)r1_;
        *(uint4*)&Pt[dbase + 2 * NPAD] = *(uint4*)r2_;
        *(uint4*)&Pt[dbase + 3 * NPAD] = *(uint4*)r3_;
    }
}

// ---------------------------------------------------------------------------
// hntq_k: blocks [0,1280) = hnT transpose; [1280,1905) = Q GEMM (hn@wq.T)
// ---------------------------------------------------------------------------
__global__ __launch_bounds__(256) void hntq_k(
    const unsigned short* __restrict__ hn, unsigned short* __restrict__ hnT,
    const unsigned short* __restrict__ wqb, unsigned short* __restrict__ qb)
{
    __shared__ __align__(16) char lds[16384];
    const int t = threadIdx.x;
    const int bid = blockIdx.x;

    if (bid < 1280) {
        const int n0 = (bid % 160) * 64, b = bid / 160;
        {
            const int nl = t >> 2, cc = t & 3;
            const int n = n0 + nl;
            uint4 v[4] = {};
            if (n < N_) {
                const uint4* src = (const uint4*)(hn + ((size_t)(b * N_ + n)) * D_ + cc * 32);
                #pragma unroll
                for (int j = 0; j < 4; ++j) v[j] = src[j];
            }
            #pragma unroll
            for (int j = 0; j < 4; ++j) {
                int ch = (cc * 4 + j) ^ (nl & 15);
                *(uint4*)(lds + nl * 256 + ch * 16) = v[j];
            }
        }
        __syncthreads();
        {
            const int ebb = t >> 3, nb = t & 7;
            unsigned short r0_[8], r1_[8], r2_[8], r3_[8];
            #pragma unroll
            for (int i = 0; i < 8; ++i) {
                int n = nb * 8 + i;
                int byte_ = n * 256 + (((ebb >> 1) ^ (n & 15)) << 4) + ((ebb & 1) << 3);
                uint2 dv = *(const uint2*)(lds + byte_);
                r0_[i] = (unsigned short)(dv.x & 0xffff); r1_[i] = (unsigned short)(dv.x >> 16);
                r2_[i] = (unsigned short)(dv.y & 0xffff); r3_[i] = (unsigned short)(dv.y >> 16);
            }
            size_t dbase = ((size_t)b * 128 + ebb * 4) * NPAD + n0 + nb * 8;
            *(uint4*)&hnT[dbase]            = *(uint4*)r0_;
            *(uint4*)&hnT[dbase + NPAD]     = *(uint4*)r1_;
            *(uint4*)&hnT[dbase + 2 * NPAD] = *(uint4*)r2_;
            *(uint4*)&hnT[dbase + 3 * NPAD] = *(uint4*)r3_;
        }
        return;
    }

    // ---- Q GEMM (128x128 tile, BK=32, NSTEP=4) ----
    const int bx = bid - 1280;
    const unsigned short* Ag = hn + (size_t)bx * 128 * 128;
    const unsigned short* Wg = wqb;
    const size_t cbase = (size_t)bx * 16384;

    const int srow = t >> 1, hib = 2 * (t & 1);
    const unsigned short* aptr = Ag + (size_t)srow * 128 + hib * 8;
    const unsigned short* wptr = Wg + (size_t)srow * 128 + hib * 8;
    const int swz = (srow >> 1) & 3;
    char* la0 = lds + srow * 64 + ((hib ^ swz) << 4);
    char* la1 = lds + srow * 64 + (((hib + 1) ^ swz) << 4);
    char* lw0 = la0 + 8192;
    char* lw1 = la1 + 8192;

    const int w = t >> 6, l = t & 63;
    const int g = l >> 4;
    const int wrow = (w & 1) * 64, wcol = (w >> 1) * 64;
    int offA[4], offW[4];
    #pragma unroll
    for (int mi = 0; mi < 4; ++mi) {
        int ra = wrow + mi * 16 + (l & 15);
        offA[mi] = ra * 64 + (((l >> 4) ^ ((ra >> 1) & 3)) << 4);
        int rw = wcol + mi * 16 + (l & 15);
        offW[mi] = 8192 + rw * 64 + (((l >> 4) ^ ((rw >> 1) & 3)) << 4);
    }

    f32x4 acc[4][4] = {};
    for (int s = 0; s < 4; ++s) {
        uint4 va0 = *(const uint4*)(aptr);
        uint4 va1 = *(const uint4*)(aptr + 8);
        uint4 vw0 = *(const uint4*)(wptr);
        uint4 vw1 = *(const uint4*)(wptr + 8);
        aptr += 32; wptr += 32;
        __syncthreads();
        *(uint4*)la0 = va0; *(uint4*)la1 = va1;
        *(uint4*)lw0 = vw0; *(uint4*)lw1 = vw1;
        __syncthreads();
        bf16x8 af[4], bfr[4];
        #pragma unroll
        for (int mi = 0; mi < 4; ++mi) {
            af[mi] = *(const bf16x8*)(lds + offA[mi]);
            bfr[mi] = *(const bf16x8*)(lds + offW[mi]);
        }
        #pragma unroll
        for (int mi = 0; mi < 4; ++mi)
            #pragma unroll
            for (int ni = 0; ni < 4; ++ni)
                acc[mi][ni] = __builtin_amdgcn_mfma_f32_16x16x32_bf16(af[mi], bfr[ni], acc[mi][ni], 0, 0, 0);
    }

    const int lrb = wrow + (g << 2);
    const int lcb = wcol + (l & 15);
    #pragma unroll
    for (int mi = 0; mi < 4; ++mi)
        #pragma unroll
        for (int ni = 0; ni < 4; ++ni) {
            const int lc = lcb + ni * 16;
            #pragma unroll
            for (int r = 0; r < 4; ++r) {
                const int lr = lrb + mi * 16 + r;
                qb[cbase + (size_t)lr * 128 + lc] = f2bf(acc[mi][ni][r]);
            }
        }
}

// ---------------------------------------------------------------------------
// MFMA GEMM. Modes: M_PROJ (split-K 16), M_SMALL.
// ---------------------------------------------------------------------------
enum { M_PROJ = 1, M_SMALL = 2 };

template<int MODE>
__global__ __launch_bounds__(256) void mgemm_k(
    const unsigned short* __restrict__ Abase, const unsigned short* __restrict__ Wbase,
    const unsigned short* __restrict__ Walt,
    float* __restrict__ Cf, unsigned short* __restrict__ Cb)
{
    constexpr int NSTEP = (MODE == M_PROJ) ? 20 : 4;
    constexpr int SA = (MODE == M_PROJ) ? NPAD : 128;
    constexpr int SB = SA;

    __shared__ __align__(16) char lds[16384];

    const int t = threadIdx.x;
    const int bx = blockIdx.x, bz = blockIdx.z;

    const unsigned short* Ag; const unsigned short* Wg; size_t cbase;
    if (MODE == M_PROJ) {
        const int b = (bz >> 4) & 7, chunk = bz & 15, which = bz >> 7;
        Ag = Abase + (size_t)which * 256 * NPAD + (size_t)bx * 128 * NPAD + chunk * 640;
        Wg = Wbase + (size_t)b * 128 * NPAD + chunk * 640;
        cbase = (size_t)bz * 32768 + (size_t)bx * 16384;
    } else {
        Ag = Abase + (size_t)bz * 2048 * 128 + (size_t)bx * 128 * 128;
        Wg = bz ? Walt : Wbase;
        cbase = (size_t)bz * 262144 + (size_t)bx * 16384;
    }

    const int srow = t >> 1, hib = 2 * (t & 1);
    const unsigned short* aptr = Ag + (size_t)srow * SA + hib * 8;
    const unsigned short* wptr = Wg + (size_t)srow * SB + hib * 8;
    const int swz = (srow >> 1) & 3;
    char* la0 = lds + srow * 64 + ((hib ^ swz) << 4);
    char* la1 = lds + srow * 64 + (((hib + 1) ^ swz) << 4);
    char* lw0 = la0 + 8192;
    char* lw1 = la1 + 8192;

    const int w = t >> 6, l = t & 63;
    const int g = l >> 4;
    const int wrow = (w & 1) * 64, wcol = (w >> 1) * 64;
    int offA[4], offW[4];
    #pragma unroll
    for (int mi = 0; mi < 4; ++mi) {
        int ra = wrow + mi * 16 + (l & 15);
        offA[mi] = ra * 64 + (((l >> 4) ^ ((ra >> 1) & 3)) << 4);
        int rw = wcol + mi * 16 + (l & 15);
        offW[mi] = 8192 + rw * 64 + (((l >> 4) ^ ((rw >> 1) & 3)) << 4);
    }

    f32x4 acc[4][4] = {};

    for (int s = 0; s < NSTEP; ++s) {
        uint4 va0 = *(const uint4*)(aptr);
        uint4 va1 = *(const uint4*)(aptr + 8);
        uint4 vw0 = *(const uint4*)(wptr);
        uint4 vw1 = *(const uint4*)(wptr + 8);
        aptr += 32; wptr += 32;
        __syncthreads();
        *(uint4*)la0 = va0; *(uint4*)la1 = va1;
        *(uint4*)lw0 = vw0; *(uint4*)lw1 = vw1;
        __syncthreads();
        bf16x8 af[4], bfr[4];
        #pragma unroll
        for (int mi = 0; mi < 4; ++mi) {
            af[mi] = *(const bf16x8*)(lds + offA[mi]);
            bfr[mi] = *(const bf16x8*)(lds + offW[mi]);
        }
        #pragma unroll
        for (int mi = 0; mi < 4; ++mi)
            #pragma unroll
            for (int ni = 0; ni < 4; ++ni)
                acc[mi][ni] = __builtin_amdgcn_mfma_f32_16x16x32_bf16(af[mi], bfr[ni], acc[mi][ni], 0, 0, 0);
    }

    const int lrb = wrow + (g << 2);
    const int lcb = wcol + (l & 15);
    #pragma unroll
    for (int mi = 0; mi < 4; ++mi) {
        #pragma unroll
        for (int ni = 0; ni < 4; ++ni) {
            const int lc = lcb + ni * 16;
            #pragma unroll
            for (int r = 0; r < 4; ++r) {
                const int lr = lrb + mi * 16 + r;
                const float v = acc[mi][ni][r];
                const size_t ci = cbase + (size_t)lr * 128 + lc;
                if (MODE == M_SMALL) Cb[ci] = f2bf(v); else Cf[ci] = v;
            }
        }
    }
}

// ---------------------------------------------------------------------------
// reduce split-K partials (16 chunks) -> lowKV bf16
// ---------------------------------------------------------------------------
__global__ __launch_bounds__(256) void reduce_k(
    const float* __restrict__ partials, unsigned short* __restrict__ lowKV)
{
    const int gid = blockIdx.x * 256 + threadIdx.x;
    const int wb = gid >> 15, r = gid & 32767;
    const float* p = partials + (size_t)wb * 16 * 32768 + r;
    float s = 0.f;
    #pragma unroll
    for (int c = 0; c < 16; ++c) s += p[c * 32768];
    lowKV[gid] = f2bf(s);
}

// ---------------------------------------------------------------------------
// Fused WO + residual + LN2 + FFN + residual + row-sum -> st.  (v2 — proven)
// WO GEMM operand-swapped; 64-row tile, 4 waves cooperate; Ald reused as A2.
// ---------------------------------------------------------------------------
__global__ __launch_bounds__(256) void wo_ffn_k(
    const unsigned short* __restrict__ attn_out, const unsigned short* __restrict__ wob,
    const float* __restrict__ wo_bias, const unsigned short* __restrict__ xeb,
    const float* __restrict__ lng, const float* __restrict__ lnb,
    const unsigned short* __restrict__ w1b, const float* __restrict__ b1,
    const unsigned short* __restrict__ w2b, const float* __restrict__ b2,
    float* __restrict__ st)
{
    __shared__ __align__(16) char lds[34816];
    const int t = threadIdx.x;
    const int w = t >> 6, l = t & 63;
    const int g = l >> 4, ql = l & 15;
    const int r0 = blockIdx.x * 64;
    const int wrow = (w & 1) * 32, wcol = (w >> 1) * 64;
    char* Ald = lds;                                 // attn-out, then LN2 out
    char* Hld = lds + 16384;
    float2* red  = (float2*)(lds + 32768);           // [2][64]
    float*  stp  = (float*) (lds + 33792);           // [64]
    float*  redF = (float*) (lds + 34048);           // [2][64]

    // ---- stage attn-out tile ----
    {
        const int rr = t >> 2, cc = t & 3;
        #pragma unroll
        for (int j = 0; j < 4; ++j) {
            const int ch = cc * 4 + j;
            const uint4 v = *(const uint4*)(attn_out + (size_t)(r0 + rr) * 128 + ch * 8);
            *(uint4*)(Ald + rr * 256 + ((ch ^ (rr & 15)) << 4)) = v;
        }
    }
    __syncthreads();

    // ---- WO GEMM (swapped): wacc[ni][mi] = C[col-group][row] ----
    f32x4 wacc[4][2] = {};
    #pragma unroll
    for (int ks = 0; ks < 4; ++ks) {
        const int e0 = ks * 32 + g * 8;
        bf16x8 af[2], wf[4];
        #pragma unroll
        for (int mi = 0; mi < 2; ++mi) {
            const int row = wrow + mi * 16 + ql;
            af[mi] = *(const bf16x8*)(Ald + row * 256 + (((e0 >> 3) ^ (row & 15)) << 4));
        }
        #pragma unroll
        for (int ni = 0; ni < 4; ++ni) {
            const int c = wcol + ni * 16 + ql;
            wf[ni] = *(const bf16x8*)(wob + (size_t)c * 128 + e0);
        }
        #pragma unroll
        for (int ni = 0; ni < 4; ++ni)
            #pragma unroll
            for (int mi = 0; mi < 2; ++mi)
                wacc[ni][mi] = __builtin_amdgcn_mfma_f32_16x16x32_bf16(wf[ni], af[mi], wacc[ni][mi], 0, 0, 0);
    }
    __syncthreads();   // Ald reads done; buffer becomes A2 (LN2 out) below

    // ---- bias + residual + row stats ----
    float rsum2[2] = {0.f, 0.f}, rsq2[2] = {0.f, 0.f};
    #pragma unroll
    for (int mi = 0; mi < 2; ++mi) {
        const int row = wrow + mi * 16 + ql;
        #pragma unroll
        for (int ni = 0; ni < 4; ++ni) {
            const int col0 = wcol + ni * 16 + g * 4;
            const float4 wb4 = *(const float4*)&wo_bias[col0];
            const uint2 xr = *(const uint2*)&xeb[(size_t)(r0 + row) * 128 + col0];
            float xv[4];
            xv[0] = bf2f((unsigned short)(xr.x & 0xffff)); xv[1] = bf2f((unsigned short)(xr.x >> 16));
            xv[2] = bf2f((unsigned short)(xr.y & 0xffff)); xv[3] = bf2f((unsigned short)(xr.y >> 16));
            const float wb_[4] = {wb4.x, wb4.y, wb4.z, wb4.w};
            #pragma unroll
            for (int j = 0; j < 4; ++j) {
                const float v = wacc[ni][mi][j] + wb_[j] + xv[j];
                wacc[ni][mi][j] = v;
                rsum2[mi] += v;
                rsq2[mi] += v * v;
            }
        }
    }
    #pragma unroll
    for (int mi = 0; mi < 2; ++mi) {
        rsum2[mi] += __shfl_xor(rsum2[mi], 16); rsum2[mi] += __shfl_xor(rsum2[mi], 32);
        rsq2[mi]  += __shfl_xor(rsq2[mi], 16);  rsq2[mi]  += __shfl_xor(rsq2[mi], 32);
    }
    if (g == 0) {
        #pragma unroll
        for (int mi = 0; mi < 2; ++mi) {
            const int row = wrow + mi * 16 + ql;
            float2 e; e.x = rsum2[mi]; e.y = rsq2[mi];
            red[(w >> 1) * 64 + row] = e;
        }
    }
    __syncthreads();

    // ---- LN apply -> A2 (= Ald region); save tot per row ----
    #pragma unroll
    for (int mi = 0; mi < 2; ++mi) {
        const int row = wrow + mi * 16 + ql;
        const float2 e0 = red[row], e1 = red[64 + row];
        const float tot = e0.x + e1.x;
        const float mu = tot * (1.f / 128.f);
        const float var = (e0.y + e1.y) * (1.f / 128.f) - mu * mu;
        const float rstd = rsqrtf(var + 1e-5f);
        if (g == 0 && (w >> 1) == 0) stp[row] = tot;
        #pragma unroll
        for (int ni = 0; ni < 4; ++ni) {
            const int col0 = wcol + ni * 16 + g * 4;
            const float4 lg4 = *(const float4*)&lng[col0];
            const float4 lb4 = *(const float4*)&lnb[col0];
            const float lg_[4] = {lg4.x, lg4.y, lg4.z, lg4.w};
            const float lb_[4] = {lb4.x, lb4.y, lb4.z, lb4.w};
            float h_[4];
            #pragma unroll
            for (int j = 0; j < 4; ++j)
                h_[j] = (wacc[ni][mi][j] - mu) * rstd * lg_[j] + lb_[j];
            uint2 pk;
            pk.x = pack2(h_[0], h_[1]);
            pk.y = pack2(h_[2], h_[3]);
            const int chunk = col0 >> 3;
            const int sub = (col0 & 4) << 1;
            *(uint2*)(Ald + row * 256 + ((chunk ^ (row & 15)) << 4) + sub) = pk;
        }
    }
    __syncthreads();

    // ---- FFN (4 hidden chunks of 128); A2 = Ald ----
    f32x4 accF[2][4] = {};
    #pragma unroll
    for (int hc = 0; hc < 4; ++hc) {
        f32x4 hacc[4][2] = {};
        #pragma unroll
        for (int ks = 0; ks < 4; ++ks) {
            const int e0 = ks * 32 + g * 8;
            bf16x8 hf[2], wf1[4];
            #pragma unroll
            for (int mi = 0; mi < 2; ++mi) {
                const int row = wrow + mi * 16 + ql;
                hf[mi] = *(const bf16x8*)(Ald + row * 256 + (((e0 >> 3) ^ (row & 15)) << 4));
            }
            #pragma unroll
            for (int ni = 0; ni < 4; ++ni) {
                const int c = hc * 128 + wcol + ni * 16 + ql;
                wf1[ni] = *(const bf16x8*)(w1b + (size_t)c * 128 + e0);
            }
            #pragma unroll
            for (int ni = 0; ni < 4; ++ni)
                #pragma unroll
                for (int mi = 0; mi < 2; ++mi)
                    hacc[ni][mi] = __builtin_amdgcn_mfma_f32_16x16x32_bf16(wf1[ni], hf[mi], hacc[ni][mi], 0, 0, 0);
        }
        #pragma unroll
        for (int ni = 0; ni < 4; ++ni) {
            const int colb = wcol + ni * 16 + g * 4;
            const float4 bb = *(const float4*)&b1[hc * 128 + colb];
            const int chunk = colb >> 3;
            const int sub = (colb & 4) << 1;
            #pragma unroll
            for (int mi = 0; mi < 2; ++mi) {
                const int row = wrow + mi * 16 + ql;
                uint2 pk;
                pk.x = pack2(gelu_tanh(hacc[ni][mi][0] + bb.x), gelu_tanh(hacc[ni][mi][1] + bb.y));
                pk.y = pack2(gelu_tanh(hacc[ni][mi][2] + bb.z), gelu_tanh(hacc[ni][mi][3] + bb.w));
                *(uint2*)(Hld + row * 256 + ((chunk ^ (row & 7)) << 4) + sub) = pk;
            }
        }
        __syncthreads();
        #pragma unroll
        for (int ks = 0; ks < 4; ++ks) {
            const int e0 = ks * 32 + g * 8;
            bf16x8 ah[2], wf2[4];
            #pragma unroll
            for (int mi = 0; mi < 2; ++mi) {
                const int row = wrow + mi * 16 + ql;
                ah[mi] = *(const bf16x8*)(Hld + row * 256 + (((e0 >> 3) ^ (row & 7)) << 4));
            }
            #pragma unroll
            for (int ni = 0; ni < 4; ++ni) {
                const int c = wcol + ni * 16 + ql;
                wf2[ni] = *(const bf16x8*)(w2b + (size_t)c * 512 + hc * 128 + e0);
            }
            #pragma unroll
            for (int mi = 0; mi < 2; ++mi)
                #pragma unroll
                for (int ni = 0; ni < 4; ++ni)
                    accF[mi][ni] = __builtin_amdgcn_mfma_f32_16x16x32_bf16(ah[mi], wf2[ni], accF[mi][ni], 0, 0, 0);
        }
        __syncthreads();
    }

    // ---- final row-sum: st = sum(ffn + b2) + tot(=128*mu) ----
    float b2_c[4];
    #pragma unroll
    for (int ni = 0; ni < 4; ++ni) b2_c[ni] = b2[wcol + ni * 16 + ql];
    float rF[2][4];
    #pragma unroll
    for (int mi = 0; mi < 2; ++mi)
        #pragma unroll
        for (int r = 0; r < 4; ++r) rF[mi][r] = 0.f;
    #pragma unroll
    for (int mi = 0; mi < 2; ++mi)
        #pragma unroll
        for (int ni = 0; ni < 4; ++ni)
            #pragma unroll
            for (int r = 0; r < 4; ++r)
                rF[mi][r] += accF[mi][ni][r] + b2_c[ni];
    #pragma unroll
    for (int mi = 0; mi < 2; ++mi)
        #pragma unroll
        for (int r = 0; r < 4; ++r) {
            float s_ = rF[mi][r];
            #pragma unroll
            for (int off = 1; off < 16; off <<= 1) s_ += __shfl_xor(s_, off);
            rF[mi][r] = s_;
        }
    if (ql == 0) {
        #pragma unroll
        for (int mi = 0; mi < 2; ++mi)
            #pragma unroll
            for (int r = 0; r < 4; ++r)
                redF[(w >> 1) * 64 + wrow + mi * 16 + g * 4 + r] = rF[mi][r];
    }
    __syncthreads();
    if (t < 64) {
        const float total = redF[t] + redF[64 + t] + stp[t];
        const int grow = r0 + t;
        const int bidx = grow / N_;
        const int n = grow - bidx * N_;
        st[(size_t)n * 8 + bidx] = total;
    }
}

// ---------------------------------------------------------------------------
// MFMA attention (K_lds swizzle (r&3)<<4 within 64B rows).
// ---------------------------------------------------------------------------
__global__ __launch_bounds__(256) void attn_mfma_k(
    const unsigned short* __restrict__ q, const unsigned short* __restrict__ kv,
    unsigned short* __restrict__ outp)
{
    __shared__ __align__(16) char lds[65536];
    const int t = threadIdx.x;
    const int w = t >> 6, l = t & 63;
    const int g = l >> 4, ql = l & 15;
    const int h = blockIdx.y, b = blockIdx.z;
    const int q0 = blockIdx.x * 256;
    const float SC = 0.17677669529663687f;   // 1/sqrt(32)

    #pragma unroll
    for (int i = 0; i < 4; ++i) {
        const int r = (t >> 2) + 64 * i;
        const uint4 v = *(const uint4*)(kv + ((size_t)(b * 256 + r) * 128 + h * 32) + (t & 3) * 8);
        *(uint4*)(lds + r * 64 + (((t & 3) * 16) ^ ((r & 3) << 4))) = v;
    }
    {
        const int kp = t & 127, dhalf = t >> 7;
        const unsigned short* vsrc = kv + 262144 + ((size_t)(b * 256 + 2 * kp) * 128 + h * 32 + 16 * dhalf);
        uint4 a0 = *(const uint4*)(vsrc);
        uint4 a1 = *(const uint4*)(vsrc + 8);
        uint4 c0 = *(const uint4*)(vsrc + 128);
        uint4 c1 = *(const uint4*)(vsrc + 136);
        const unsigned short* pa0 = (const unsigned short*)&a0;
        const unsigned short* pa1 = (const unsigned short*)&a1;
        const unsigned short* pc0 = (const unsigned short*)&c0;
        const unsigned short* pc1 = (const unsigned short*)&c1;
        #pragma unroll
        for (int j = 0; j < 8; ++j) {
            const int row = 16 * dhalf + j;
            unsigned u = (unsigned)pa0[j] | ((unsigned)pc0[j] << 16);
            *(unsigned*)(lds + 16384 + row * 512 + ((4 * kp) ^ ((row & 7) << 4))) = u;
        }
        #pragma unroll
        for (int j = 0; j < 8; ++j) {
            const int row = 16 * dhalf + 8 + j;
            unsigned u = (unsigned)pa1[j] | ((unsigned)pc1[j] << 16);
            *(unsigned*)(lds + 16384 + row * 512 + ((4 * kp) ^ ((row & 7) << 4))) = u;
        }
    }
    bf16x8 qfr[4];
    #pragma unroll
    for (int qf = 0; qf < 4; ++qf) {
        int n = q0 + w * 64 + qf * 16 + ql;
        if (n >= N_) n = N_ - 1;
        qfr[qf] = *(const bf16x8*)(q + ((size_t)(b * N_ + n) * 128 + h * 32 + g * 8));
    }
    __syncthreads();

    char* Pw = lds + 32768 + w * 8192;
    f32x4 oacc[2][4] = {};
    float m_run[4], l_run[4];
    #pragma unroll
    for (int qf = 0; qf < 4; ++qf) { m_run[qf] = -1e30f; l_run[qf] = 0.f; }

    for (int kt = 0; kt < 4; ++kt) {
        const int kb = kt * 64;
        bf16x8 kfr[4];
        #pragma unroll
        for (int kf = 0; kf < 4; ++kf) {
            const int r = kb + kf * 16 + ql;
            kfr[kf] = *(const bf16x8*)(lds + r * 64 + ((g * 16) ^ ((r & 3) << 4)));
        }
        f32x4 s_[4][4];
        #pragma unroll
        for (int kf = 0; kf < 4; ++kf)
            #pragma unroll
            for (int qf = 0; qf < 4; ++qf) {
                f32x4 z = {0.f, 0.f, 0.f, 0.f};
                s_[kf][qf] = __builtin_amdgcn_mfma_f32_16x16x32_bf16(kfr[kf], qfr[qf], z, 0, 0, 0);
            }
        #pragma unroll
        for (int qf = 0; qf < 4; ++qf) {
            float mx = -1e30f;
            #pragma unroll
            for (int kf = 0; kf < 4; ++kf)
                #pragma unroll
                for (int r = 0; r < 4; ++r) mx = fmaxf(mx, s_[kf][qf][r]);
            mx = fmaxf(mx, __shfl_xor(mx, 16));
            mx = fmaxf(mx, __shfl_xor(mx, 32));
            mx *= SC;
            if (mx > m_run[qf]) {
                const float corr = __expf(m_run[qf] - mx);
                l_run[qf] *= corr;
                #pragma unroll
                for (int df = 0; df < 2; ++df) {
                    oacc[df][qf][0] *= corr; oacc[df][qf][1] *= corr;
                    oacc[df][qf][2] *= corr; oacc[df][qf][3] *= corr;
                }
                m_run[qf] = mx;
            }
            float p_[4][4]; float ssum = 0.f;
            #pragma unroll
            for (int kf = 0; kf < 4; ++kf)
                #pragma unroll
                for (int r = 0; r < 4; ++r) {
                    const float pv = __expf(s_[kf][qf][r] * SC - m_run[qf]);
                    p_[kf][r] = pv; ssum += pv;
                }
            ssum += __shfl_xor(ssum, 16);
            ssum += __shfl_xor(ssum, 32);
            l_run[qf] += ssum;
            const int qrow = qf * 16 + ql;
            #pragma unroll
            for (int kf = 0; kf < 4; ++kf) {
                uint2 pk;
                pk.x = pack2(p_[kf][0], p_[kf][1]);
                pk.y = pack2(p_[kf][2], p_[kf][3]);
                *(uint2*)(Pw + qrow * 128 + ((kf * 32 + g * 8) ^ ((qrow & 7) << 4))) = pk;
            }
        }
        asm volatile("s_waitcnt lgkmcnt(0)" ::: "memory");
        __builtin_amdgcn_sched_barrier(0);
        #pragma unroll
        for (int ks = 0; ks < 2; ++ks) {
            bf16x8 vt_[2];
            #pragma unroll
            for (int df = 0; df < 2; ++df) {
                const int row = df * 16 + ql;
                vt_[df] = *(const bf16x8*)(lds + 16384 + row * 512 +
                           ((kb * 2 + ks * 64 + g * 16) ^ ((row & 7) << 4)));
            }
            #pragma unroll
            for (int qf = 0; qf < 4; ++qf) {
                const int qrow = qf * 16 + ql;
                bf16x8 pf = *(const bf16x8*)(Pw + qrow * 128 + ((ks * 64 + g * 16) ^ ((qrow & 7) << 4)));
                #pragma unroll
                for (int df = 0; df < 2; ++df)
                    oacc[df][qf] = __builtin_amdgcn_mfma_f32_16x16x32_bf16(vt_[df], pf, oacc[df][qf], 0, 0, 0);
            }
        }
        asm volatile("s_waitcnt lgkmcnt(0)" ::: "memory");
        __builtin_amdgcn_sched_barrier(0);
    }

    float inv_[4];
    #pragma unroll
    for (int qf = 0; qf < 4; ++qf) inv_[qf] = 1.f / l_run[qf];
    #pragma unroll
    for (int qf = 0; qf < 4; ++qf) {
        const int qrow = qf * 16 + ql;
        #pragma unroll
        for (int df = 0; df < 2; ++df) {
            const unsigned lo = pack2(oacc[df][qf][0] * inv_[qf], oacc[df][qf][1] * inv_[qf]);
            const unsigned hi = pack2(oacc[df][qf][2] * inv_[qf], oacc[df][qf][3] * inv_[qf]);
            *(unsigned*)(Pw + qrow * 64 + ((df * 32 + g * 8) ^ ((qrow & 3) << 4))) = lo;
            *(unsigned*)(Pw + qrow * 64 + ((df * 32 + g * 8 + 4) ^ ((qrow & 3) << 4))) = hi;
        }
    }
    asm volatile("s_waitcnt lgkmcnt(0)" ::: "memory");
    __builtin_amdgcn_sched_barrier(0);
    #pragma unroll
    for (int pp = 0; pp < 4; ++pp) {
        const int qrow = pp * 16 + (l >> 2), c = l & 3;
        const uint4 v = *(const uint4*)(Pw + qrow * 64 + ((c * 16) ^ ((qrow & 3) << 4)));
        const int n = q0 + w * 64 + qrow;
        if (n < N_)
            *(uint4*)(outp + ((size_t)(b * N_ + n) * 128 + h * 32 + c * 8)) = v;
    }
}

// ---------------------------------------------------------------------------
// fc2_k + combine (see R7)
// ---------------------------------------------------------------------------
__global__ __launch_bounds__(256) void fc2_k(
    const float* __restrict__ st, const float* __restrict__ fcw,
    float* __restrict__ part)
{
    __shared__ float s_lds[16000];   // [2000][8]
    const int t = threadIdx.x;
    const int m0 = blockIdx.x * 64;
    const int n0 = blockIdx.y * 2000;

    const float4* src = (const float4*)(st + (size_t)n0 * 8);
    #pragma unroll 4
    for (int i = t; i < 4000; i += 256)
        ((float4*)s_lds)[i] = src[i];
    __syncthreads();

    const int mloc = t >> 2, q = t & 3;
    const int m = m0 + mloc;
    float acc[8] = {};
    if (m < M_) {
        const float* wrow = fcw + (size_t)m * N_ + n0;
        for (int k = 0; k < 125; ++k) {
            const int nn = q * 4 + k * 16;
            const float4 wv = *(const float4*)(wrow + nn);
            const float wl[4] = {wv.x, wv.y, wv.z, wv.w};
            #pragma unroll
            for (int j = 0; j < 4; ++j) {
                const float4 sa = *(const float4*)(s_lds + (nn + j) * 8);
                const float4 sb = *(const float4*)(s_lds + (nn + j) * 8 + 4);
                acc[0] = fmaf(wl[j], sa.x, acc[0]); acc[1] = fmaf(wl[j], sa.y, acc[1]);
                acc[2] = fmaf(wl[j], sa.z, acc[2]); acc[3] = fmaf(wl[j], sa.w, acc[3]);
                acc[4] = fmaf(wl[j], sb.x, acc[4]); acc[5] = fmaf(wl[j], sb.y, acc[5]);
                acc[6] = fmaf(wl[j], sb.z, acc[6]); acc[7] = fmaf(wl[j], sb.w, acc[7]);
            }
        }
    }
    #pragma unroll
    for (int j = 0; j < 8; ++j) {
        acc[j] += __shfl_xor(acc[j], 1);
        acc[j] += __shfl_xor(acc[j], 2);
    }
    if (q == 0 && m < M_) {
        float* pb = part + (size_t)blockIdx.y * 40000 + m;
        #pragma unroll
        for (int bb = 0; bb < 8; ++bb) pb[bb * 5000] = acc[bb];
    }
}

__global__ __launch_bounds__(256) void fc_combine_k(
    const float* __restrict__ part, const float* __restrict__ fcb,
    float* __restrict__ out)
{
    const int i = blockIdx.x * 256 + threadIdx.x;
    if (i >= 40000) return;
    float s = 0.f;
    #pragma unroll
    for (int c = 0; c < 5; ++c) s += part[c * 40000 + i];
    const int m = i % 5000;
    out[i] = s + 128.f * fcb[m];
}

// ---------------------------------------------------------------------------
extern "C" void kernel_launch(void* const* d_in, const int* in_sizes, int n_in,
                              void* d_out, int out_size, void* d_ws, size_t ws_size,
                              hipStream_t stream)
{
    const float* x      = (const float*)d_in[0];
    const float* emb_w  = (const float*)d_in[1];
    const float* emb_b  = (const float*)d_in[2];
    const float* ln1_g  = (const float*)d_in[3];
    const float* ln1_b  = (const float*)d_in[4];
    const float* wq     = (const float*)d_in[5];
    const float* wk     = (const float*)d_in[6];
    const float* wv     = (const float*)d_in[7];
    const float* projk  = (const float*)d_in[8];
    const float* projv  = (const float*)d_in[9];
    const float* wo     = (const float*)d_in[10];
    const float* wo_b   = (const float*)d_in[11];
    const float* ln2_g  = (const float*)d_in[12];
    const float* ln2_b  = (const float*)d_in[13];
    const float* w1     = (const float*)d_in[14];
    const float* b1     = (const float*)d_in[15];
    const float* w2     = (const float*)d_in[16];
    const float* b2     = (const float*)d_in[17];
    const float* fcw    = (const float*)d_in[18];
    const float* fcb    = (const float*)d_in[19];
    float* out = (float*)d_out;

    char* W = (char*)d_ws;
    unsigned short* xeb      = (unsigned short*)W;                     // 20,480,000
    unsigned short* hnb      = (unsigned short*)(W + 40960000);        // 20,480,000
    char*           region   = W + 61440000;
    unsigned short* qb       = (unsigned short*)region;                // 20,480,000
    unsigned short* hnT      = (unsigned short*)(region + 20480000);   // 20,971,520
    unsigned short* Pt       = (unsigned short*)(region + 41451520);   // 10,485,760
    float*          partials = (float*)(region + 51937280);            // 33,554,432 (16 chunks)
    unsigned short* lowKV    = (unsigned short*)(W + 146931712);       // 1,048,576
    unsigned short* klowb    = (unsigned short*)(W + 147980288);       // [2][2048][128] bf16
    unsigned short* wqb      = (unsigned short*)(W + 150077440);
    unsigned short* wkb      = wqb + 16384;
    unsigned short* wvb      = wkb + 16384;
    unsigned short* wob      = wvb + 16384;
    unsigned short* w1b      = wob + 16384;
    unsigned short* w2b      = w1b + 65536;
    float*          st       = (float*)(W + 150470656);                // 320,000
    float*          fcpart   = (float*)(W + 150790656);                // 800,000

    prep_embed_k<<<20832, 256, 0, stream>>>(x, emb_w, emb_b, ln1_g, ln1_b, xeb, hnb,
                                            wq, wk, wv, wo, w1, w2,
                                            wqb, wkb, wvb, wob, w1b, w2b,
                                            projk, projv, Pt);
    hntq_k<<<1905, 256, 0, stream>>>(hnb, hnT, wqb, qb);
    mgemm_k<M_PROJ><<<dim3(2, 1, 256), 256, 0, stream>>>(Pt, hnT, nullptr, partials, nullptr);
    reduce_k<<<2048, 256, 0, stream>>>(partials, lowKV);
    mgemm_k<M_SMALL><<<dim3(16, 1, 2), 256, 0, stream>>>(lowKV, wkb, wvb, nullptr, klowb);
    attn_mfma_k<<<dim3(40, H_, B_), 256, 0, stream>>>(qb, klowb, hnb);
    wo_ffn_k<<<1250, 256, 0, stream>>>(hnb, wob, wo_b, xeb, ln2_g, ln2_b, w1b, b1, w2b, b2, st);
    fc2_k<<<dim3(79, 5), 256, 0, stream>>>(st, fcw, fcpart);
    fc_combine_k<<<157, 256, 0, stream>>>(fcpart, fcb, out);
}

// Round 14
// 282.637 us; speedup vs baseline: 1.3693x; 1.1115x over previous
//
#include <hip/hip_runtime.h>

constexpr int B_ = 8, N_ = 10000, D_ = 128, H_ = 4, K_ = 256, M_ = 5000, DFF_ = 512;
constexpr int NPAD = 10240;   // n padded to multiple of 32 for MFMA K-loop

typedef __attribute__((ext_vector_type(8))) short bf16x8;
typedef __attribute__((ext_vector_type(4))) float f32x4;

__device__ __forceinline__ float bf2f(unsigned short u) {
    unsigned x = ((unsigned)u) << 16; float f; __builtin_memcpy(&f, &x, 4); return f;
}
__device__ __forceinline__ unsigned short f2bf(float f) {
    unsigned x; __builtin_memcpy(&x, &f, 4);
    x = (x + 0x7fffu + ((x >> 16) & 1u)) >> 16;   // RNE
    return (unsigned short)x;
}
__device__ __forceinline__ unsigned pack2(float a, float b) {
    return (unsigned)f2bf(a) | ((unsigned)f2bf(b) << 16);
}
// tanh-form GELU (max |err| ~3e-4 vs erf form, << bf16 quantization)
__device__ __forceinline__ float gelu_tanh(float v) {
    const float z = 0.7978845608028654f * fmaf(0.044715f * v, v * v, v);
    const float e = __expf(2.f * z);
    const float th = fmaf(-2.f, __builtin_amdgcn_rcpf(1.f + e), 1.f);
    return 0.5f * v * (1.f + th);
}

// ---------------------------------------------------------------------------
// prep_embed_k: blocks [0,20000) = embed+PE+LN1; [20000,20192) = weight cvt
// (wq/wk/wv linear; wo/w1/w2 FRAGMENT-PACKED for coalesced wave reads);
// [20192,20832) = Pt transpose.
// Packed layouts (8-elem groups):
//   wob:  p = (((wc2*4+ni)*4+ks)*16+ql)*4+g            (2048 groups)
//   w1b:  p = ((((hc*2+wc2)*4+ni)*4+ks)*16+ql)*4+g     (8192 groups)
//   w2b:  p = ((((wc2*4+ni)*4+hc)*4+ks)*16+ql)*4+g     (8192 groups)
// One packed fragment block = 64 groups = 512 elems (1KB); reader stride 512.
// ---------------------------------------------------------------------------
__global__ __launch_bounds__(256) void prep_embed_k(
    const float* __restrict__ x, const float* __restrict__ ew, const float* __restrict__ eb,
    const float* __restrict__ g1, const float* __restrict__ bb1,
    unsigned short* __restrict__ xeb, unsigned short* __restrict__ hnb,
    const float* __restrict__ wq, const float* __restrict__ wk, const float* __restrict__ wv,
    const float* __restrict__ wo, const float* __restrict__ w1, const float* __restrict__ w2,
    unsigned short* __restrict__ wqb, unsigned short* __restrict__ wkb, unsigned short* __restrict__ wvb,
    unsigned short* __restrict__ wob, unsigned short* __restrict__ w1b, unsigned short* __restrict__ w2b,
    const float* __restrict__ pK, const float* __restrict__ pV, unsigned short* __restrict__ Pt)
{
    __shared__ __align__(16) char lds[16384];
    const int t = threadIdx.x;
    const int bid = blockIdx.x;

    if (bid < 20000) {
        const int r = bid * 4 + (t >> 6);
        const int lane = t & 63;
        const int n = r % N_;
        const float xv = x[r];
        const float ang = (float)n * expf((float)lane * -0.14391156829962788f);
        float sv, cv; sincosf(ang, &sv, &cv);
        const int d0 = 2 * lane;
        float e0 = xv * ew[d0]     + eb[d0]     + sv;
        float e1 = xv * ew[d0 + 1] + eb[d0 + 1] + cv;
        float sum = e0 + e1, sq = e0 * e0 + e1 * e1;
        #pragma unroll
        for (int off = 32; off; off >>= 1) { sum += __shfl_xor(sum, off); sq += __shfl_xor(sq, off); }
        const float mu = sum * (1.f / 128.f);
        const float var = sq * (1.f / 128.f) - mu * mu;
        const float rs = rsqrtf(var + 1e-5f);
        const size_t base = (size_t)r * D_ + d0;
        *(unsigned*)&xeb[base] = pack2(e0, e1);
        *(unsigned*)&hnb[base] = pack2((e0 - mu) * rs * g1[d0] + bb1[d0],
                                       (e1 - mu) * rs * g1[d0 + 1] + bb1[d0 + 1]);
        return;
    }

    const int flat = bid - 20000;
    if (flat < 192) {
        const int by = flat / 32, bx = flat % 32;
        if (by < 3) {
            const float* s = (by == 0) ? wq : (by == 1) ? wk : wv;
            unsigned short* d = (by == 0) ? wqb : (by == 1) ? wkb : wvb;
            const int idx = (bx * 256 + t) * 8;
            if (idx >= 16384) return;
            float4 a = *(const float4*)(s + idx);
            float4 b = *(const float4*)(s + idx + 4);
            uint4 p;
            p.x = pack2(a.x, a.y); p.y = pack2(a.z, a.w);
            p.z = pack2(b.x, b.y); p.w = pack2(b.z, b.w);
            *(uint4*)(d + idx) = p;
        } else if (by == 3) {
            const int p = bx * 256 + t;
            if (p >= 2048) return;
            const int g = p & 3, ql = (p >> 2) & 15, ks = (p >> 6) & 3, ni = (p >> 8) & 3, wc2 = (p >> 10) & 1;
            const int c = wc2 * 64 + ni * 16 + ql;
            const int e0 = ks * 32 + g * 8;
            const float4 a = *(const float4*)(wo + c * 128 + e0);
            const float4 b = *(const float4*)(wo + c * 128 + e0 + 4);
            uint4 pk;
            pk.x = pack2(a.x, a.y); pk.y = pack2(a.z, a.w);
            pk.z = pack2(b.x, b.y); pk.w = pack2(b.z, b.w);
            *(uint4*)(wob + p * 8) = pk;
        } else if (by == 4) {
            const int p = bx * 256 + t;
            const int g = p & 3, ql = (p >> 2) & 15, ks = (p >> 6) & 3, ni = (p >> 8) & 3,
                      wc2 = (p >> 10) & 1, hc = (p >> 11) & 3;
            const int c = hc * 128 + wc2 * 64 + ni * 16 + ql;
            const int e0 = ks * 32 + g * 8;
            const float4 a = *(const float4*)(w1 + c * 128 + e0);
            const float4 b = *(const float4*)(w1 + c * 128 + e0 + 4);
            uint4 pk;
            pk.x = pack2(a.x, a.y); pk.y = pack2(a.z, a.w);
            pk.z = pack2(b.x, b.y); pk.w = pack2(b.z, b.w);
            *(uint4*)(w1b + p * 8) = pk;
        } else {
            const int p = bx * 256 + t;
            const int g = p & 3, ql = (p >> 2) & 15, ks = (p >> 6) & 3, hc = (p >> 8) & 3,
                      ni = (p >> 10) & 3, wc2 = (p >> 12) & 1;
            const int c = wc2 * 64 + ni * 16 + ql;
            const int e = hc * 128 + ks * 32 + g * 8;
            const float4 a = *(const float4*)(w2 + c * 512 + e);
            const float4 b = *(const float4*)(w2 + c * 512 + e + 4);
            uint4 pk;
            pk.x = pack2(a.x, a.y); pk.y = pack2(a.z, a.w);
            pk.z = pack2(b.x, b.y); pk.w = pack2(b.z, b.w);
            *(uint4*)(w2b + p * 8) = pk;
        }
        return;
    }

    // ---- ptt part ----
    const int f = flat - 192;
    const int bx = f % 160, rest = f / 160;
    const int n0 = bx * 64, k0 = (rest & 1) * 128, which = rest >> 1;
    const float* P = which ? pV : pK;
    {
        const int nl = t >> 2, cc = t & 3;
        const int n = n0 + nl;
        uint4 v[4] = {};
        if (n < N_) {
            const float4* src = (const float4*)(P + (size_t)n * K_ + k0 + cc * 32);
            #pragma unroll
            for (int j = 0; j < 4; ++j) {
                float4 a = src[2 * j], b = src[2 * j + 1];
                uint4 p; p.x = pack2(a.x, a.y); p.y = pack2(a.z, a.w);
                p.z = pack2(b.x, b.y); p.w = pack2(b.z, b.w);
                v[j] = p;
            }
        }
        #pragma unroll
        for (int j = 0; j < 4; ++j) {
            int ch = (cc * 4 + j) ^ (nl & 15);
            *(uint4*)(lds + nl * 256 + ch * 16) = v[j];
        }
    }
    __syncthreads();
    {
        const int ebb = t >> 3, nb = t & 7;
        unsigned short r0_[8], r1_[8], r2_[8], r3_[8];
        #pragma unroll
        for (int i = 0; i < 8; ++i) {
            int n = nb * 8 + i;
            int byte_ = n * 256 + (((ebb >> 1) ^ (n & 15)) << 4) + ((ebb & 1) << 3);
            uint2 dv = *(const uint2*)(lds + byte_);
            r0_[i] = (unsigned short)(dv.x & 0xffff); r1_[i] = (unsigned short)(dv.x >> 16);
            r2_[i] = (unsigned short)(dv.y & 0xffff); r3_[i] = (unsigned short)(dv.y >> 16);
        }
        size_t dbase = ((size_t)which * 256 + k0 + ebb * 4) * NPAD + n0 + nb * 8;
        *(uint4*)&Pt[dbase]            = *(uint4*)r0_;
        *(uint4*)&Pt[dbase + NPAD]     = *(uint4*)r1_;
        *(uint4*)&Pt[dbase + 2 * NPAD] = *(uint4*)r2_;
        *(uint4*)&Pt[dbase + 3 * NPAD] = *(uint4*)r3_;
    }
}

// ---------------------------------------------------------------------------
// hntq_k: blocks [0,1280) = hnT transpose; [1280,1905) = Q GEMM (hn@wq.T)
// ---------------------------------------------------------------------------
__global__ __launch_bounds__(256) void hntq_k(
    const unsigned short* __restrict__ hn, unsigned short* __restrict__ hnT,
    const unsigned short* __restrict__ wqb, unsigned short* __restrict__ qb)
{
    __shared__ __align__(16) char lds[16384];
    const int t = threadIdx.x;
    const int bid = blockIdx.x;

    if (bid < 1280) {
        const int n0 = (bid % 160) * 64, b = bid / 160;
        {
            const int nl = t >> 2, cc = t & 3;
            const int n = n0 + nl;
            uint4 v[4] = {};
            if (n < N_) {
                const uint4* src = (const uint4*)(hn + ((size_t)(b * N_ + n)) * D_ + cc * 32);
                #pragma unroll
                for (int j = 0; j < 4; ++j) v[j] = src[j];
            }
            #pragma unroll
            for (int j = 0; j < 4; ++j) {
                int ch = (cc * 4 + j) ^ (nl & 15);
                *(uint4*)(lds + nl * 256 + ch * 16) = v[j];
            }
        }
        __syncthreads();
        {
            const int ebb = t >> 3, nb = t & 7;
            unsigned short r0_[8], r1_[8], r2_[8], r3_[8];
            #pragma unroll
            for (int i = 0; i < 8; ++i) {
                int n = nb * 8 + i;
                int byte_ = n * 256 + (((ebb >> 1) ^ (n & 15)) << 4) + ((ebb & 1) << 3);
                uint2 dv = *(const uint2*)(lds + byte_);
                r0_[i] = (unsigned short)(dv.x & 0xffff); r1_[i] = (unsigned short)(dv.x >> 16);
                r2_[i] = (unsigned short)(dv.y & 0xffff); r3_[i] = (unsigned short)(dv.y >> 16);
            }
            size_t dbase = ((size_t)b * 128 + ebb * 4) * NPAD + n0 + nb * 8;
            *(uint4*)&hnT[dbase]            = *(uint4*)r0_;
            *(uint4*)&hnT[dbase + NPAD]     = *(uint4*)r1_;
            *(uint4*)&hnT[dbase + 2 * NPAD] = *(uint4*)r2_;
            *(uint4*)&hnT[dbase + 3 * NPAD] = *(uint4*)r3_;
        }
        return;
    }

    // ---- Q GEMM (128x128 tile, BK=32, NSTEP=4) ----
    const int bx = bid - 1280;
    const unsigned short* Ag = hn + (size_t)bx * 128 * 128;
    const unsigned short* Wg = wqb;
    const size_t cbase = (size_t)bx * 16384;

    const int srow = t >> 1, hib = 2 * (t & 1);
    const unsigned short* aptr = Ag + (size_t)srow * 128 + hib * 8;
    const unsigned short* wptr = Wg + (size_t)srow * 128 + hib * 8;
    const int swz = (srow >> 1) & 3;
    char* la0 = lds + srow * 64 + ((hib ^ swz) << 4);
    char* la1 = lds + srow * 64 + (((hib + 1) ^ swz) << 4);
    char* lw0 = la0 + 8192;
    char* lw1 = la1 + 8192;

    const int w = t >> 6, l = t & 63;
    const int g = l >> 4;
    const int wrow = (w & 1) * 64, wcol = (w >> 1) * 64;
    int offA[4], offW[4];
    #pragma unroll
    for (int mi = 0; mi < 4; ++mi) {
        int ra = wrow + mi * 16 + (l & 15);
        offA[mi] = ra * 64 + (((l >> 4) ^ ((ra >> 1) & 3)) << 4);
        int rw = wcol + mi * 16 + (l & 15);
        offW[mi] = 8192 + rw * 64 + (((l >> 4) ^ ((rw >> 1) & 3)) << 4);
    }

    f32x4 acc[4][4] = {};
    for (int s = 0; s < 4; ++s) {
        uint4 va0 = *(const uint4*)(aptr);
        uint4 va1 = *(const uint4*)(aptr + 8);
        uint4 vw0 = *(const uint4*)(wptr);
        uint4 vw1 = *(const uint4*)(wptr + 8);
        aptr += 32; wptr += 32;
        __syncthreads();
        *(uint4*)la0 = va0; *(uint4*)la1 = va1;
        *(uint4*)lw0 = vw0; *(uint4*)lw1 = vw1;
        __syncthreads();
        bf16x8 af[4], bfr[4];
        #pragma unroll
        for (int mi = 0; mi < 4; ++mi) {
            af[mi] = *(const bf16x8*)(lds + offA[mi]);
            bfr[mi] = *(const bf16x8*)(lds + offW[mi]);
        }
        #pragma unroll
        for (int mi = 0; mi < 4; ++mi)
            #pragma unroll
            for (int ni = 0; ni < 4; ++ni)
                acc[mi][ni] = __builtin_amdgcn_mfma_f32_16x16x32_bf16(af[mi], bfr[ni], acc[mi][ni], 0, 0, 0);
    }

    const int lrb = wrow + (g << 2);
    const int lcb = wcol + (l & 15);
    #pragma unroll
    for (int mi = 0; mi < 4; ++mi)
        #pragma unroll
        for (int ni = 0; ni < 4; ++ni) {
            const int lc = lcb + ni * 16;
            #pragma unroll
            for (int r = 0; r < 4; ++r) {
                const int lr = lrb + mi * 16 + r;
                qb[cbase + (size_t)lr * 128 + lc] = f2bf(acc[mi][ni][r]);
            }
        }
}

// ---------------------------------------------------------------------------
// MFMA GEMM. Modes: M_PROJ (split-K 16), M_SMALL.
// ---------------------------------------------------------------------------
enum { M_PROJ = 1, M_SMALL = 2 };

template<int MODE>
__global__ __launch_bounds__(256) void mgemm_k(
    const unsigned short* __restrict__ Abase, const unsigned short* __restrict__ Wbase,
    const unsigned short* __restrict__ Walt,
    float* __restrict__ Cf, unsigned short* __restrict__ Cb)
{
    constexpr int NSTEP = (MODE == M_PROJ) ? 20 : 4;
    constexpr int SA = (MODE == M_PROJ) ? NPAD : 128;
    constexpr int SB = SA;

    __shared__ __align__(16) char lds[16384];

    const int t = threadIdx.x;
    const int bx = blockIdx.x, bz = blockIdx.z;

    const unsigned short* Ag; const unsigned short* Wg; size_t cbase;
    if (MODE == M_PROJ) {
        const int b = (bz >> 4) & 7, chunk = bz & 15, which = bz >> 7;
        Ag = Abase + (size_t)which * 256 * NPAD + (size_t)bx * 128 * NPAD + chunk * 640;
        Wg = Wbase + (size_t)b * 128 * NPAD + chunk * 640;
        cbase = (size_t)bz * 32768 + (size_t)bx * 16384;
    } else {
        Ag = Abase + (size_t)bz * 2048 * 128 + (size_t)bx * 128 * 128;
        Wg = bz ? Walt : Wbase;
        cbase = (size_t)bz * 262144 + (size_t)bx * 16384;
    }

    const int srow = t >> 1, hib = 2 * (t & 1);
    const unsigned short* aptr = Ag + (size_t)srow * SA + hib * 8;
    const unsigned short* wptr = Wg + (size_t)srow * SB + hib * 8;
    const int swz = (srow >> 1) & 3;
    char* la0 = lds + srow * 64 + ((hib ^ swz) << 4);
    char* la1 = lds + srow * 64 + (((hib + 1) ^ swz) << 4);
    char* lw0 = la0 + 8192;
    char* lw1 = la1 + 8192;

    const int w = t >> 6, l = t & 63;
    const int g = l >> 4;
    const int wrow = (w & 1) * 64, wcol = (w >> 1) * 64;
    int offA[4], offW[4];
    #pragma unroll
    for (int mi = 0; mi < 4; ++mi) {
        int ra = wrow + mi * 16 + (l & 15);
        offA[mi] = ra * 64 + (((l >> 4) ^ ((ra >> 1) & 3)) << 4);
        int rw = wcol + mi * 16 + (l & 15);
        offW[mi] = 8192 + rw * 64 + (((l >> 4) ^ ((rw >> 1) & 3)) << 4);
    }

    f32x4 acc[4][4] = {};

    for (int s = 0; s < NSTEP; ++s) {
        uint4 va0 = *(const uint4*)(aptr);
        uint4 va1 = *(const uint4*)(aptr + 8);
        uint4 vw0 = *(const uint4*)(wptr);
        uint4 vw1 = *(const uint4*)(wptr + 8);
        aptr += 32; wptr += 32;
        __syncthreads();
        *(uint4*)la0 = va0; *(uint4*)la1 = va1;
        *(uint4*)lw0 = vw0; *(uint4*)lw1 = vw1;
        __syncthreads();
        bf16x8 af[4], bfr[4];
        #pragma unroll
        for (int mi = 0; mi < 4; ++mi) {
            af[mi] = *(const bf16x8*)(lds + offA[mi]);
            bfr[mi] = *(const bf16x8*)(lds + offW[mi]);
        }
        #pragma unroll
        for (int mi = 0; mi < 4; ++mi)
            #pragma unroll
            for (int ni = 0; ni < 4; ++ni)
                acc[mi][ni] = __builtin_amdgcn_mfma_f32_16x16x32_bf16(af[mi], bfr[ni], acc[mi][ni], 0, 0, 0);
    }

    const int lrb = wrow + (g << 2);
    const int lcb = wcol + (l & 15);
    #pragma unroll
    for (int mi = 0; mi < 4; ++mi) {
        #pragma unroll
        for (int ni = 0; ni < 4; ++ni) {
            const int lc = lcb + ni * 16;
            #pragma unroll
            for (int r = 0; r < 4; ++r) {
                const int lr = lrb + mi * 16 + r;
                const float v = acc[mi][ni][r];
                const size_t ci = cbase + (size_t)lr * 128 + lc;
                if (MODE == M_SMALL) Cb[ci] = f2bf(v); else Cf[ci] = v;
            }
        }
    }
}

// ---------------------------------------------------------------------------
// reduce split-K partials (16 chunks) -> lowKV bf16
// ---------------------------------------------------------------------------
__global__ __launch_bounds__(256) void reduce_k(
    const float* __restrict__ partials, unsigned short* __restrict__ lowKV)
{
    const int gid = blockIdx.x * 256 + threadIdx.x;
    const int wb = gid >> 15, r = gid & 32767;
    const float* p = partials + (size_t)wb * 16 * 32768 + r;
    float s = 0.f;
    #pragma unroll
    for (int c = 0; c < 16; ++c) s += p[c * 32768];
    lowKV[gid] = f2bf(s);
}

// ---------------------------------------------------------------------------
// Fused WO + residual + LN2 + FFN + residual + row-sum -> st.  (v2 + packed W)
// W fragments from FRAGMENT-PACKED wob/w1b/w2b: stride 512 elems (1KB)/block.
// ---------------------------------------------------------------------------
__global__ __launch_bounds__(256) void wo_ffn_k(
    const unsigned short* __restrict__ attn_out, const unsigned short* __restrict__ wob,
    const float* __restrict__ wo_bias, const unsigned short* __restrict__ xeb,
    const float* __restrict__ lng, const float* __restrict__ lnb,
    const unsigned short* __restrict__ w1b, const float* __restrict__ b1,
    const unsigned short* __restrict__ w2b, const float* __restrict__ b2,
    float* __restrict__ st)
{
    __shared__ __align__(16) char lds[34816];
    const int t = threadIdx.x;
    const int w = t >> 6, l = t & 63;
    const int g = l >> 4, ql = l & 15;
    const int r0 = blockIdx.x * 64;
    const int wrow = (w & 1) * 32, wcol = (w >> 1) * 64;
    const int wc2 = w >> 1;
    const int fragbase = (ql * 4 + g) * 8;           // lane offset within 512-elem packed block
    char* Ald = lds;                                 // attn-out, then LN2 out
    char* Hld = lds + 16384;
    float2* red  = (float2*)(lds + 32768);           // [2][64]
    float*  stp  = (float*) (lds + 33792);           // [64]
    float*  redF = (float*) (lds + 34048);           // [2][64]

    // ---- stage attn-out tile ----
    {
        const int rr = t >> 2, cc = t & 3;
        #pragma unroll
        for (int j = 0; j < 4; ++j) {
            const int ch = cc * 4 + j;
            const uint4 v = *(const uint4*)(attn_out + (size_t)(r0 + rr) * 128 + ch * 8);
            *(uint4*)(Ald + rr * 256 + ((ch ^ (rr & 15)) << 4)) = v;
        }
    }
    __syncthreads();

    // ---- WO GEMM (swapped): wacc[ni][mi] = C[col-group][row] ----
    f32x4 wacc[4][2] = {};
    #pragma unroll
    for (int ks = 0; ks < 4; ++ks) {
        const int e0 = ks * 32 + g * 8;
        bf16x8 af[2], wf[4];
        #pragma unroll
        for (int mi = 0; mi < 2; ++mi) {
            const int row = wrow + mi * 16 + ql;
            af[mi] = *(const bf16x8*)(Ald + row * 256 + (((e0 >> 3) ^ (row & 15)) << 4));
        }
        #pragma unroll
        for (int ni = 0; ni < 4; ++ni)
            wf[ni] = *(const bf16x8*)(wob + (size_t)(((wc2 * 4 + ni) * 4 + ks) * 512) + fragbase);
        #pragma unroll
        for (int ni = 0; ni < 4; ++ni)
            #pragma unroll
            for (int mi = 0; mi < 2; ++mi)
                wacc[ni][mi] = __builtin_amdgcn_mfma_f32_16x16x32_bf16(wf[ni], af[mi], wacc[ni][mi], 0, 0, 0);
    }
    __syncthreads();   // Ald reads done; buffer becomes A2 (LN2 out) below

    // ---- bias + residual + row stats ----
    float rsum2[2] = {0.f, 0.f}, rsq2[2] = {0.f, 0.f};
    #pragma unroll
    for (int mi = 0; mi < 2; ++mi) {
        const int row = wrow + mi * 16 + ql;
        #pragma unroll
        for (int ni = 0; ni < 4; ++ni) {
            const int col0 = wcol + ni * 16 + g * 4;
            const float4 wb4 = *(const float4*)&wo_bias[col0];
            const uint2 xr = *(const uint2*)&xeb[(size_t)(r0 + row) * 128 + col0];
            float xv[4];
            xv[0] = bf2f((unsigned short)(xr.x & 0xffff)); xv[1] = bf2f((unsigned short)(xr.x >> 16));
            xv[2] = bf2f((unsigned short)(xr.y & 0xffff)); xv[3] = bf2f((unsigned short)(xr.y >> 16));
            const float wb_[4] = {wb4.x, wb4.y, wb4.z, wb4.w};
            #pragma unroll
            for (int j = 0; j < 4; ++j) {
                const float v = wacc[ni][mi][j] + wb_[j] + xv[j];
                wacc[ni][mi][j] = v;
                rsum2[mi] += v;
                rsq2[mi] += v * v;
            }
        }
    }
    #pragma unroll
    for (int mi = 0; mi < 2; ++mi) {
        rsum2[mi] += __shfl_xor(rsum2[mi], 16); rsum2[mi] += __shfl_xor(rsum2[mi], 32);
        rsq2[mi]  += __shfl_xor(rsq2[mi], 16);  rsq2[mi]  += __shfl_xor(rsq2[mi], 32);
    }
    if (g == 0) {
        #pragma unroll
        for (int mi = 0; mi < 2; ++mi) {
            const int row = wrow + mi * 16 + ql;
            float2 e; e.x = rsum2[mi]; e.y = rsq2[mi];
            red[(w >> 1) * 64 + row] = e;
        }
    }
    __syncthreads();

    // ---- LN apply -> A2 (= Ald region); save tot per row ----
    #pragma unroll
    for (int mi = 0; mi < 2; ++mi) {
        const int row = wrow + mi * 16 + ql;
        const float2 e0 = red[row], e1 = red[64 + row];
        const float tot = e0.x + e1.x;
        const float mu = tot * (1.f / 128.f);
        const float var = (e0.y + e1.y) * (1.f / 128.f) - mu * mu;
        const float rstd = rsqrtf(var + 1e-5f);
        if (g == 0 && (w >> 1) == 0) stp[row] = tot;
        #pragma unroll
        for (int ni = 0; ni < 4; ++ni) {
            const int col0 = wcol + ni * 16 + g * 4;
            const float4 lg4 = *(const float4*)&lng[col0];
            const float4 lb4 = *(const float4*)&lnb[col0];
            const float lg_[4] = {lg4.x, lg4.y, lg4.z, lg4.w};
            const float lb_[4] = {lb4.x, lb4.y, lb4.z, lb4.w};
            float h_[4];
            #pragma unroll
            for (int j = 0; j < 4; ++j)
                h_[j] = (wacc[ni][mi][j] - mu) * rstd * lg_[j] + lb_[j];
            uint2 pk;
            pk.x = pack2(h_[0], h_[1]);
            pk.y = pack2(h_[2], h_[3]);
            const int chunk = col0 >> 3;
            const int sub = (col0 & 4) << 1;
            *(uint2*)(Ald + row * 256 + ((chunk ^ (row & 15)) << 4) + sub) = pk;
        }
    }
    __syncthreads();

    // ---- FFN (4 hidden chunks of 128); A2 = Ald ----
    f32x4 accF[2][4] = {};
    #pragma unroll
    for (int hc = 0; hc < 4; ++hc) {
        f32x4 hacc[4][2] = {};
        #pragma unroll
        for (int ks = 0; ks < 4; ++ks) {
            const int e0 = ks * 32 + g * 8;
            bf16x8 hf[2], wf1[4];
            #pragma unroll
            for (int mi = 0; mi < 2; ++mi) {
                const int row = wrow + mi * 16 + ql;
                hf[mi] = *(const bf16x8*)(Ald + row * 256 + (((e0 >> 3) ^ (row & 15)) << 4));
            }
            #pragma unroll
            for (int ni = 0; ni < 4; ++ni)
                wf1[ni] = *(const bf16x8*)(w1b + (size_t)((((hc * 2 + wc2) * 4 + ni) * 4 + ks) * 512) + fragbase);
            #pragma unroll
            for (int ni = 0; ni < 4; ++ni)
                #pragma unroll
                for (int mi = 0; mi < 2; ++mi)
                    hacc[ni][mi] = __builtin_amdgcn_mfma_f32_16x16x32_bf16(wf1[ni], hf[mi], hacc[ni][mi], 0, 0, 0);
        }
        #pragma unroll
        for (int ni = 0; ni < 4; ++ni) {
            const int colb = wcol + ni * 16 + g * 4;
            const float4 bb = *(const float4*)&b1[hc * 128 + colb];
            const int chunk = colb >> 3;
            const int sub = (colb & 4) << 1;
            #pragma unroll
            for (int mi = 0; mi < 2; ++mi) {
                const int row = wrow + mi * 16 + ql;
                uint2 pk;
                pk.x = pack2(gelu_tanh(hacc[ni][mi][0] + bb.x), gelu_tanh(hacc[ni][mi][1] + bb.y));
                pk.y = pack2(gelu_tanh(hacc[ni][mi][2] + bb.z), gelu_tanh(hacc[ni][mi][3] + bb.w));
                *(uint2*)(Hld + row * 256 + ((chunk ^ (row & 7)) << 4) + sub) = pk;
            }
        }
        __syncthreads();
        #pragma unroll
        for (int ks = 0; ks < 4; ++ks) {
            const int e0 = ks * 32 + g * 8;
            bf16x8 ah[2], wf2[4];
            #pragma unroll
            for (int mi = 0; mi < 2; ++mi) {
                const int row = wrow + mi * 16 + ql;
                ah[mi] = *(const bf16x8*)(Hld + row * 256 + (((e0 >> 3) ^ (row & 7)) << 4));
            }
            #pragma unroll
            for (int ni = 0; ni < 4; ++ni)
                wf2[ni] = *(const bf16x8*)(w2b + (size_t)((((wc2 * 4 + ni) * 4 + hc) * 4 + ks) * 512) + fragbase);
            #pragma unroll
            for (int mi = 0; mi < 2; ++mi)
                #pragma unroll
                for (int ni = 0; ni < 4; ++ni)
                    accF[mi][ni] = __builtin_amdgcn_mfma_f32_16x16x32_bf16(ah[mi], wf2[ni], accF[mi][ni], 0, 0, 0);
        }
        __syncthreads();
    }

    // ---- final row-sum: st = sum(ffn + b2) + tot(=128*mu) ----
    float b2_c[4];
    #pragma unroll
    for (int ni = 0; ni < 4; ++ni) b2_c[ni] = b2[wcol + ni * 16 + ql];
    float rF[2][4];
    #pragma unroll
    for (int mi = 0; mi < 2; ++mi)
        #pragma unroll
        for (int r = 0; r < 4; ++r) rF[mi][r] = 0.f;
    #pragma unroll
    for (int mi = 0; mi < 2; ++mi)
        #pragma unroll
        for (int ni = 0; ni < 4; ++ni)
            #pragma unroll
            for (int r = 0; r < 4; ++r)
                rF[mi][r] += accF[mi][ni][r] + b2_c[ni];
    #pragma unroll
    for (int mi = 0; mi < 2; ++mi)
        #pragma unroll
        for (int r = 0; r < 4; ++r) {
            float s_ = rF[mi][r];
            #pragma unroll
            for (int off = 1; off < 16; off <<= 1) s_ += __shfl_xor(s_, off);
            rF[mi][r] = s_;
        }
    if (ql == 0) {
        #pragma unroll
        for (int mi = 0; mi < 2; ++mi)
            #pragma unroll
            for (int r = 0; r < 4; ++r)
                redF[(w >> 1) * 64 + wrow + mi * 16 + g * 4 + r] = rF[mi][r];
    }
    __syncthreads();
    if (t < 64) {
        const float total = redF[t] + redF[64 + t] + stp[t];
        const int grow = r0 + t;
        const int bidx = grow / N_;
        const int n = grow - bidx * N_;
        st[(size_t)n * 8 + bidx] = total;
    }
}

// ---------------------------------------------------------------------------
// MFMA attention (K_lds swizzle (r&3)<<4 within 64B rows).
// ---------------------------------------------------------------------------
__global__ __launch_bounds__(256) void attn_mfma_k(
    const unsigned short* __restrict__ q, const unsigned short* __restrict__ kv,
    unsigned short* __restrict__ outp)
{
    __shared__ __align__(16) char lds[65536];
    const int t = threadIdx.x;
    const int w = t >> 6, l = t & 63;
    const int g = l >> 4, ql = l & 15;
    const int h = blockIdx.y, b = blockIdx.z;
    const int q0 = blockIdx.x * 256;
    const float SC = 0.17677669529663687f;   // 1/sqrt(32)

    #pragma unroll
    for (int i = 0; i < 4; ++i) {
        const int r = (t >> 2) + 64 * i;
        const uint4 v = *(const uint4*)(kv + ((size_t)(b * 256 + r) * 128 + h * 32) + (t & 3) * 8);
        *(uint4*)(lds + r * 64 + (((t & 3) * 16) ^ ((r & 3) << 4))) = v;
    }
    {
        const int kp = t & 127, dhalf = t >> 7;
        const unsigned short* vsrc = kv + 262144 + ((size_t)(b * 256 + 2 * kp) * 128 + h * 32 + 16 * dhalf);
        uint4 a0 = *(const uint4*)(vsrc);
        uint4 a1 = *(const uint4*)(vsrc + 8);
        uint4 c0 = *(const uint4*)(vsrc + 128);
        uint4 c1 = *(const uint4*)(vsrc + 136);
        const unsigned short* pa0 = (const unsigned short*)&a0;
        const unsigned short* pa1 = (const unsigned short*)&a1;
        const unsigned short* pc0 = (const unsigned short*)&c0;
        const unsigned short* pc1 = (const unsigned short*)&c1;
        #pragma unroll
        for (int j = 0; j < 8; ++j) {
            const int row = 16 * dhalf + j;
            unsigned u = (unsigned)pa0[j] | ((unsigned)pc0[j] << 16);
            *(unsigned*)(lds + 16384 + row * 512 + ((4 * kp) ^ ((row & 7) << 4))) = u;
        }
        #pragma unroll
        for (int j = 0; j < 8; ++j) {
            const int row = 16 * dhalf + 8 + j;
            unsigned u = (unsigned)pa1[j] | ((unsigned)pc1[j] << 16);
            *(unsigned*)(lds + 16384 + row * 512 + ((4 * kp) ^ ((row & 7) << 4))) = u;
        }
    }
    bf16x8 qfr[4];
    #pragma unroll
    for (int qf = 0; qf < 4; ++qf) {
        int n = q0 + w * 64 + qf * 16 + ql;
        if (n >= N_) n = N_ - 1;
        qfr[qf] = *(const bf16x8*)(q + ((size_t)(b * N_ + n) * 128 + h * 32 + g * 8));
    }
    __syncthreads();

    char* Pw = lds + 32768 + w * 8192;
    f32x4 oacc[2][4] = {};
    float m_run[4], l_run[4];
    #pragma unroll
    for (int qf = 0; qf < 4; ++qf) { m_run[qf] = -1e30f; l_run[qf] = 0.f; }

    for (int kt = 0; kt < 4; ++kt) {
        const int kb = kt * 64;
        bf16x8 kfr[4];
        #pragma unroll
        for (int kf = 0; kf < 4; ++kf) {
            const int r = kb + kf * 16 + ql;
            kfr[kf] = *(const bf16x8*)(lds + r * 64 + ((g * 16) ^ ((r & 3) << 4)));
        }
        f32x4 s_[4][4];
        #pragma unroll
        for (int kf = 0; kf < 4; ++kf)
            #pragma unroll
            for (int qf = 0; qf < 4; ++qf) {
                f32x4 z = {0.f, 0.f, 0.f, 0.f};
                s_[kf][qf] = __builtin_amdgcn_mfma_f32_16x16x32_bf16(kfr[kf], qfr[qf], z, 0, 0, 0);
            }
        #pragma unroll
        for (int qf = 0; qf < 4; ++qf) {
            float mx = -1e30f;
            #pragma unroll
            for (int kf = 0; kf < 4; ++kf)
                #pragma unroll
                for (int r = 0; r < 4; ++r) mx = fmaxf(mx, s_[kf][qf][r]);
            mx = fmaxf(mx, __shfl_xor(mx, 16));
            mx = fmaxf(mx, __shfl_xor(mx, 32));
            mx *= SC;
            if (mx > m_run[qf]) {
                const float corr = __expf(m_run[qf] - mx);
                l_run[qf] *= corr;
                #pragma unroll
                for (int df = 0; df < 2; ++df) {
                    oacc[df][qf][0] *= corr; oacc[df][qf][1] *= corr;
                    oacc[df][qf][2] *= corr; oacc[df][qf][3] *= corr;
                }
                m_run[qf] = mx;
            }
            float p_[4][4]; float ssum = 0.f;
            #pragma unroll
            for (int kf = 0; kf < 4; ++kf)
                #pragma unroll
                for (int r = 0; r < 4; ++r) {
                    const float pv = __expf(s_[kf][qf][r] * SC - m_run[qf]);
                    p_[kf][r] = pv; ssum += pv;
                }
            ssum += __shfl_xor(ssum, 16);
            ssum += __shfl_xor(ssum, 32);
            l_run[qf] += ssum;
            const int qrow = qf * 16 + ql;
            #pragma unroll
            for (int kf = 0; kf < 4; ++kf) {
                uint2 pk;
                pk.x = pack2(p_[kf][0], p_[kf][1]);
                pk.y = pack2(p_[kf][2], p_[kf][3]);
                *(uint2*)(Pw + qrow * 128 + ((kf * 32 + g * 8) ^ ((qrow & 7) << 4))) = pk;
            }
        }
        asm volatile("s_waitcnt lgkmcnt(0)" ::: "memory");
        __builtin_amdgcn_sched_barrier(0);
        #pragma unroll
        for (int ks = 0; ks < 2; ++ks) {
            bf16x8 vt_[2];
            #pragma unroll
            for (int df = 0; df < 2; ++df) {
                const int row = df * 16 + ql;
                vt_[df] = *(const bf16x8*)(lds + 16384 + row * 512 +
                           ((kb * 2 + ks * 64 + g * 16) ^ ((row & 7) << 4)));
            }
            #pragma unroll
            for (int qf = 0; qf < 4; ++qf) {
                const int qrow = qf * 16 + ql;
                bf16x8 pf = *(const bf16x8*)(Pw + qrow * 128 + ((ks * 64 + g * 16) ^ ((qrow & 7) << 4)));
                #pragma unroll
                for (int df = 0; df < 2; ++df)
                    oacc[df][qf] = __builtin_amdgcn_mfma_f32_16x16x32_bf16(vt_[df], pf, oacc[df][qf], 0, 0, 0);
            }
        }
        asm volatile("s_waitcnt lgkmcnt(0)" ::: "memory");
        __builtin_amdgcn_sched_barrier(0);
    }

    float inv_[4];
    #pragma unroll
    for (int qf = 0; qf < 4; ++qf) inv_[qf] = 1.f / l_run[qf];
    #pragma unroll
    for (int qf = 0; qf < 4; ++qf) {
        const int qrow = qf * 16 + ql;
        #pragma unroll
        for (int df = 0; df < 2; ++df) {
            const unsigned lo = pack2(oacc[df][qf][0] * inv_[qf], oacc[df][qf][1] * inv_[qf]);
            const unsigned hi = pack2(oacc[df][qf][2] * inv_[qf], oacc[df][qf][3] * inv_[qf]);
            *(unsigned*)(Pw + qrow * 64 + ((df * 32 + g * 8) ^ ((qrow & 3) << 4))) = lo;
            *(unsigned*)(Pw + qrow * 64 + ((df * 32 + g * 8 + 4) ^ ((qrow & 3) << 4))) = hi;
        }
    }
    asm volatile("s_waitcnt lgkmcnt(0)" ::: "memory");
    __builtin_amdgcn_sched_barrier(0);
    #pragma unroll
    for (int pp = 0; pp < 4; ++pp) {
        const int qrow = pp * 16 + (l >> 2), c = l & 3;
        const uint4 v = *(const uint4*)(Pw + qrow * 64 + ((c * 16) ^ ((qrow & 3) << 4)));
        const int n = q0 + w * 64 + qrow;
        if (n < N_)
            *(uint4*)(outp + ((size_t)(b * N_ + n) * 128 + h * 32 + c * 8)) = v;
    }
}

// ---------------------------------------------------------------------------
// fc2_k + combine (see R7)
// ---------------------------------------------------------------------------
__global__ __launch_bounds__(256) void fc2_k(
    const float* __restrict__ st, const float* __restrict__ fcw,
    float* __restrict__ part)
{
    __shared__ float s_lds[16000];   // [2000][8]
    const int t = threadIdx.x;
    const int m0 = blockIdx.x * 64;
    const int n0 = blockIdx.y * 2000;

    const float4* src = (const float4*)(st + (size_t)n0 * 8);
    #pragma unroll 4
    for (int i = t; i < 4000; i += 256)
        ((float4*)s_lds)[i] = src[i];
    __syncthreads();

    const int mloc = t >> 2, q = t & 3;
    const int m = m0 + mloc;
    float acc[8] = {};
    if (m < M_) {
        const float* wrow = fcw + (size_t)m * N_ + n0;
        for (int k = 0; k < 125; ++k) {
            const int nn = q * 4 + k * 16;
            const float4 wv = *(const float4*)(wrow + nn);
            const float wl[4] = {wv.x, wv.y, wv.z, wv.w};
            #pragma unroll
            for (int j = 0; j < 4; ++j) {
                const float4 sa = *(const float4*)(s_lds + (nn + j) * 8);
                const float4 sb = *(const float4*)(s_lds + (nn + j) * 8 + 4);
                acc[0] = fmaf(wl[j], sa.x, acc[0]); acc[1] = fmaf(wl[j], sa.y, acc[1]);
                acc[2] = fmaf(wl[j], sa.z, acc[2]); acc[3] = fmaf(wl[j], sa.w, acc[3]);
                acc[4] = fmaf(wl[j], sb.x, acc[4]); acc[5] = fmaf(wl[j], sb.y, acc[5]);
                acc[6] = fmaf(wl[j], sb.z, acc[6]); acc[7] = fmaf(wl[j], sb.w, acc[7]);
            }
        }
    }
    #pragma unroll
    for (int j = 0; j < 8; ++j) {
        acc[j] += __shfl_xor(acc[j], 1);
        acc[j] += __shfl_xor(acc[j], 2);
    }
    if (q == 0 && m < M_) {
        float* pb = part + (size_t)blockIdx.y * 40000 + m;
        #pragma unroll
        for (int bb = 0; bb < 8; ++bb) pb[bb * 5000] = acc[bb];
    }
}

__global__ __launch_bounds__(256) void fc_combine_k(
    const float* __restrict__ part, const float* __restrict__ fcb,
    float* __restrict__ out)
{
    const int i = blockIdx.x * 256 + threadIdx.x;
    if (i >= 40000) return;
    float s = 0.f;
    #pragma unroll
    for (int c = 0; c < 5; ++c) s += part[c * 40000 + i];
    const int m = i % 5000;
    out[i] = s + 128.f * fcb[m];
}

// ---------------------------------------------------------------------------
extern "C" void kernel_launch(void* const* d_in, const int* in_sizes, int n_in,
                              void* d_out, int out_size, void* d_ws, size_t ws_size,
                              hipStream_t stream)
{
    const float* x      = (const float*)d_in[0];
    const float* emb_w  = (const float*)d_in[1];
    const float* emb_b  = (const float*)d_in[2];
    const float* ln1_g  = (const float*)d_in[3];
    const float* ln1_b  = (const float*)d_in[4];
    const float* wq     = (const float*)d_in[5];
    const float* wk     = (const float*)d_in[6];
    const float* wv     = (const float*)d_in[7];
    const float* projk  = (const float*)d_in[8];
    const float* projv  = (const float*)d_in[9];
    const float* wo     = (const float*)d_in[10];
    const float* wo_b   = (const float*)d_in[11];
    const float* ln2_g  = (const float*)d_in[12];
    const float* ln2_b  = (const float*)d_in[13];
    const float* w1     = (const float*)d_in[14];
    const float* b1     = (const float*)d_in[15];
    const float* w2     = (const float*)d_in[16];
    const float* b2     = (const float*)d_in[17];
    const float* fcw    = (const float*)d_in[18];
    const float* fcb    = (const float*)d_in[19];
    float* out = (float*)d_out;

    char* W = (char*)d_ws;
    unsigned short* xeb      = (unsigned short*)W;                     // 20,480,000
    unsigned short* hnb      = (unsigned short*)(W + 40960000);        // 20,480,000
    char*           region   = W + 61440000;
    unsigned short* qb       = (unsigned short*)region;                // 20,480,000
    unsigned short* hnT      = (unsigned short*)(region + 20480000);   // 20,971,520
    unsigned short* Pt       = (unsigned short*)(region + 41451520);   // 10,485,760
    float*          partials = (float*)(region + 51937280);            // 33,554,432 (16 chunks)
    unsigned short* lowKV    = (unsigned short*)(W + 146931712);       // 1,048,576
    unsigned short* klowb    = (unsigned short*)(W + 147980288);       // [2][2048][128] bf16
    unsigned short* wqb      = (unsigned short*)(W + 150077440);
    unsigned short* wkb      = wqb + 16384;
    unsigned short* wvb      = wkb + 16384;
    unsigned short* wob      = wvb + 16384;
    unsigned short* w1b      = wob + 16384;
    unsigned short* w2b      = w1b + 65536;
    float*          st       = (float*)(W + 150470656);                // 320,000
    float*          fcpart   = (float*)(W + 150790656);                // 800,000

    prep_embed_k<<<20832, 256, 0, stream>>>(x, emb_w, emb_b, ln1_g, ln1_b, xeb, hnb,
                                            wq, wk, wv, wo, w1, w2,
                                            wqb, wkb, wvb, wob, w1b, w2b,
                                            projk, projv, Pt);
    hntq_k<<<1905, 256, 0, stream>>>(hnb, hnT, wqb, qb);
    mgemm_k<M_PROJ><<<dim3(2, 1, 256), 256, 0, stream>>>(Pt, hnT, nullptr, partials, nullptr);
    reduce_k<<<2048, 256, 0, stream>>>(partials, lowKV);
    mgemm_k<M_SMALL><<<dim3(16, 1, 2), 256, 0, stream>>>(lowKV, wkb, wvb, nullptr, klowb);
    attn_mfma_k<<<dim3(40, H_, B_), 256, 0, stream>>>(qb, klowb, hnb);
    wo_ffn_k<<<1250, 256, 0, stream>>>(hnb, wob, wo_b, xeb, ln2_g, ln2_b, w1b, b1, w2b, b2, st);
    fc2_k<<<dim3(79, 5), 256, 0, stream>>>(st, fcw, fcpart);
    fc_combine_k<<<157, 256, 0, stream>>>(fcpart, fcb, out);
}